// Round 16
// baseline (304.295 us; speedup 1.0000x reference)
//
#include <hip/hip_runtime.h>
#include <math.h>

// Problem constants
#define BB_ 4
#define FF_ 256
#define TT_ 256
#define KK_ 8
#define CC_ 10
#define DD_ 156
#define OO_ 160   // K*C*N
#define NEGC (-1e9f)

// ---------- helpers ----------
__device__ __forceinline__ float softplusf(float x){
    return fmaxf(x, 0.f) + log1pf(expf(-fabsf(x)));
}
__device__ __forceinline__ float lse2f(float a, float b){
    float m = fmaxf(a, b);
    return m + logf(expf(a-m) + expf(b-m));
}
__device__ __forceinline__ float lse2_fast(float a, float b){
    float m = fmaxf(a, b);
    return m + __logf(__expf(a-m) + __expf(b-m));
}
__device__ __forceinline__ void lse_acc(float &m, float &s, float x){
    if (x > m){ s = s*expf(m-x) + 1.f; m = x; }
    else        s += expf(x-m);
}
__device__ __forceinline__ void lse_acc_fast(float &m, float &s, float x){
    if (x > m){ s = s*__expf(m-x) + 1.f; m = x; }
    else        s += __expf(x-m);
}
__device__ __forceinline__ void wave_lse_reduce(float &m, float &s){
    for (int off = 32; off; off >>= 1){
        float m2 = __shfl_xor(m, off);
        float s2 = __shfl_xor(s, off);
        float M  = fmaxf(m, m2);
        s = s*expf(m-M) + s2*expf(m2-M);
        m = M;
    }
}
// DPP move (compile-time ctrl). row_ror:N = 0x120+N; quad_perm[1,0,3,2] = 0xB1.
template<int CTRL>
__device__ __forceinline__ float dppf(float v){
    return __int_as_float(__builtin_amdgcn_update_dpp(
        0, __float_as_int(v), CTRL, 0xF, 0xF, false));
}
__device__ __forceinline__ float dpp_sum8(float a){
    a = a + dppf<0x122>(a);
    a = a + dppf<0x124>(a);
    a = a + dppf<0x128>(a);
    return a;
}
__device__ __forceinline__ float dpp_max8(float a){
    a = fmaxf(a, dppf<0x122>(a));
    a = fmaxf(a, dppf<0x124>(a));
    a = fmaxf(a, dppf<0x128>(a));
    return a;
}

// ---------- 1. bnstats (blocks [0,256)) ∥ logpd (blocks [256,416)) ----------
__global__ void k_bnstats_logpd(const float* __restrict__ h, float* __restrict__ meanv,
                                float* __restrict__ rstdv,
                                const float* __restrict__ conc, const float* __restrict__ rate,
                                const float* __restrict__ logit_lo1, float* __restrict__ logp_d,
                                float* __restrict__ log_lo){
    if (blockIdx.x >= FF_){
        // ---- logpd part (one wave per (k,c,n)) ----
        if (threadIdx.x >= 64) return;
        int kcn = blockIdx.x - FF_;   // (k*C+c)*2+n
        int lane = threadIdx.x;
        float a  = softplusf(conc[kcn]) + 1e-4f;
        float bb = softplusf(rate[kcn]) + 1e-4f;
        float base = a*logf(bb) - lgammaf(a);
        float vals[3]; int ds[3]; int cnt = 0;
        float m = -1e30f, s = 0.f;
        for (int i = 0; i < 3; ++i){
            int d = lane + i*64;
            if (d < DD_){
                float dv = (float)(d+1);
                float x = base + (a - 1.f)*logf(dv) - bb*dv;
                vals[cnt] = x; ds[cnt] = d; ++cnt;
                lse_acc(m, s, x);
            }
        }
        wave_lse_reduce(m, s);
        float total = m + logf(s);
        for (int i = 0; i < cnt; ++i) logp_d[kcn*DD_ + ds[i]] = vals[i] - total;
        if (lane == 0){
            float x = logit_lo1[kcn >> 1];
            float xx = (kcn & 1) ? -x : x;
            log_lo[kcn] = -softplusf(-xx);   // log_sigmoid
        }
        return;
    }
    // ---- bnstats part ----
    int f = blockIdx.x; int tid = threadIdx.x;
    float s = 0.f, s2 = 0.f;
    for (int b = 0; b < BB_; ++b){
        float v = h[(b*FF_ + f)*TT_ + tid];
        s += v; s2 += v*v;
    }
    __shared__ float rs[4], rs2[4];
    for (int off = 32; off; off >>= 1){ s += __shfl_xor(s, off); s2 += __shfl_xor(s2, off); }
    if ((tid & 63) == 0){ rs[tid>>6] = s; rs2[tid>>6] = s2; }
    __syncthreads();
    if (tid == 0){
        float S = rs[0]+rs[1]+rs[2]+rs[3];
        float S2 = rs2[0]+rs2[1]+rs2[2]+rs2[3];
        float mean = S / 1024.f;
        float var = S2 / 1024.f - mean*mean;
        meanv[f] = mean;
        rstdv[f] = rsqrtf(var + 1e-5f);
    }
}

// ---------- 2. bn apply + relu ----------
__global__ void k_bnapply(const float* __restrict__ h, const float* __restrict__ meanv,
                          const float* __restrict__ rstdv, const float* __restrict__ gamma,
                          const float* __restrict__ beta, float* __restrict__ xbn){
    int idx = blockIdx.x*256 + threadIdx.x;           // (b*F+f)*T + t
    int f = (idx >> 8) & 255;
    float x = (h[idx] - meanv[f]) * rstdv[f] * gamma[f] + beta[f];
    xbn[idx] = fmaxf(x, 0.f);
}

// ---------- 3. emission GEMM, LDS-tiled, + fused inclusive prefix over t ----------
// 40 blocks: (b, o-chunk of 16). X staged in 32x256 tiles; W transposed f-major
// (float4 broadcast reads). xbn read once per block (10 MB total vs 160 MB).
__global__ __launch_bounds__(256) void k_gemm_em(const float* __restrict__ xbn,
                          const float* __restrict__ w_em,
                          const float* __restrict__ b_em, float* __restrict__ Pout){
    __shared__ float Xs[32][TT_];     // 32 KB
    __shared__ float Wt[32][16];      // f-major, 2 KB
    __shared__ float wsum[16][4];
    int blk = blockIdx.x;             // b*10 + ochunk
    int b = blk / 10, o0 = (blk % 10) * 16;
    int tid = threadIdx.x;
    int wv = tid >> 6, ln = tid & 63;
    const float* xsrc = xbn + b*FF_*TT_;
    float acc[16];
    #pragma unroll
    for (int o = 0; o < 16; ++o) acc[o] = 0.f;
    for (int kc = 0; kc < 8; ++kc){
        __syncthreads();   // protect Xs/Wt from previous chunk's readers
        for (int idx = tid; idx < 32*256; idx += 256){
            int f = idx >> 8, t2 = idx & 255;
            Xs[f][t2] = xsrc[(kc*32 + f)*TT_ + t2];
        }
        for (int idx = tid; idx < 32*16; idx += 256){
            int f = idx >> 4, o = idx & 15;
            Wt[f][o] = w_em[(o0 + o)*FF_ + kc*32 + f];
        }
        __syncthreads();
        #pragma unroll 4
        for (int f = 0; f < 32; ++f){
            float xv = Xs[f][tid];
            float4 w0 = *reinterpret_cast<const float4*>(&Wt[f][0]);
            float4 w1 = *reinterpret_cast<const float4*>(&Wt[f][4]);
            float4 w2 = *reinterpret_cast<const float4*>(&Wt[f][8]);
            float4 w3 = *reinterpret_cast<const float4*>(&Wt[f][12]);
            acc[0]  = fmaf(w0.x, xv, acc[0]);  acc[1]  = fmaf(w0.y, xv, acc[1]);
            acc[2]  = fmaf(w0.z, xv, acc[2]);  acc[3]  = fmaf(w0.w, xv, acc[3]);
            acc[4]  = fmaf(w1.x, xv, acc[4]);  acc[5]  = fmaf(w1.y, xv, acc[5]);
            acc[6]  = fmaf(w1.z, xv, acc[6]);  acc[7]  = fmaf(w1.w, xv, acc[7]);
            acc[8]  = fmaf(w2.x, xv, acc[8]);  acc[9]  = fmaf(w2.y, xv, acc[9]);
            acc[10] = fmaf(w2.z, xv, acc[10]); acc[11] = fmaf(w2.w, xv, acc[11]);
            acc[12] = fmaf(w3.x, xv, acc[12]); acc[13] = fmaf(w3.y, xv, acc[13]);
            acc[14] = fmaf(w3.z, xv, acc[14]); acc[15] = fmaf(w3.w, xv, acc[15]);
        }
    }
    __syncthreads();
    // fused inclusive prefix over t per o: wave shuffle-scan + cross-wave carry
    #pragma unroll 1
    for (int o = 0; o < 16; ++o){
        float v = acc[o] + b_em[o0 + o];
        #pragma unroll
        for (int off = 1; off < 64; off <<= 1){
            float u = __shfl_up(v, off);
            if (ln >= off) v += u;
        }
        if (ln == 63) wsum[o][wv] = v;
        __syncthreads();
        float carry = 0.f;
        for (int w = 0; w < 4; ++w) if (w < wv) carry += wsum[o][w];
        v += carry;
        Pout[(b*OO_ + o0 + o)*TT_ + tid] = v;
    }
}

// ---------- 5. attention pool -> log_pi (one block per b) ----------
__global__ void k_attnpool(const float* __restrict__ xm, const float* __restrict__ xmT,
                           const float* __restrict__ q,
                           const float* __restrict__ w_attn, const float* __restrict__ b_attn,
                           const float* __restrict__ w_k, const float* __restrict__ b_k,
                           float* __restrict__ log_pi){
    int b = blockIdx.x; int tid = threadIdx.x;
    __shared__ float sc[256], pooled[256], zs[256], red[8];
    const float* xb = xm + b*FF_*TT_;
    float acc = 0.f;
    for (int f = 0; f < FF_; ++f) acc += q[f] * xb[f*TT_ + tid];
    sc[tid] = acc; __syncthreads();
    float v = sc[tid];
    float m = v;
    for (int off = 32; off; off >>= 1) m = fmaxf(m, __shfl_xor(m, off));
    if ((tid & 63) == 0) red[tid>>6] = m;
    __syncthreads();
    m = fmaxf(fmaxf(red[0], red[1]), fmaxf(red[2], red[3]));
    float e = expf(v - m);
    float ssum = e;
    for (int off = 32; off; off >>= 1) ssum += __shfl_xor(ssum, off);
    if ((tid & 63) == 0) red[4 + (tid>>6)] = ssum;
    __syncthreads();
    ssum = red[4]+red[5]+red[6]+red[7];
    __syncthreads();
    sc[tid] = e / ssum; __syncthreads();
    const float* xT = xmT + b*TT_*FF_;
    float pacc = 0.f;
    for (int t2 = 0; t2 < TT_; ++t2) pacc += xT[t2*FF_ + tid] * sc[t2];
    pooled[tid] = pacc; __syncthreads();
    int wv = tid >> 6; int ln = tid & 63;
    for (int ii = 0; ii < 64; ++ii){
        int i = wv*64 + ii;
        float za = 0.f;
        #pragma unroll
        for (int ff = 0; ff < 4; ++ff) za += pooled[ln + 64*ff] * w_attn[i*FF_ + ln + 64*ff];
        for (int off = 32; off; off >>= 1) za += __shfl_xor(za, off);
        if (ln == 0) zs[i] = za + b_attn[i];
    }
    __syncthreads();
    if (wv == 0){
        for (int kk2 = 0; kk2 < KK_; ++kk2){
            float za = 0.f;
            #pragma unroll
            for (int ff = 0; ff < 4; ++ff) za += zs[ln + 64*ff] * w_k[kk2*FF_ + ln + 64*ff];
            for (int off = 32; off; off >>= 1) za += __shfl_xor(za, off);
            if (ln == 0) red[kk2] = za + b_k[kk2];
        }
    }
    __syncthreads();
    if (tid == 0){
        float mm = -1e30f;
        for (int i = 0; i < KK_; ++i) mm = fmaxf(mm, red[i]);
        float su = 0.f;
        for (int i = 0; i < KK_; ++i) su += expf(red[i] - mm);
        sc[0] = mm + logf(su);
    }
    __syncthreads();
    if (tid < KK_) log_pi[b*KK_ + tid] = red[tid] - sc[0];
}

// ---------- 8. MEGA kernel: HSMM scan (blocks [0,160), wave 0 only)
// ∥ mixture GEMM (blocks [160,1184)) — byte-identical to rounds 13-15 ----------
__global__ __launch_bounds__(256) void k_scan_mix(const float* __restrict__ P,
                          const float* __restrict__ logp_d,
                          const float* __restrict__ log_lo, const float* __restrict__ log_A,
                          float* __restrict__ s_hist, float* __restrict__ Zout,
                          float* __restrict__ beta,
                          const float* __restrict__ h, const float* __restrict__ w_mix,
                          const float* __restrict__ b_mix, float* __restrict__ xm,
                          float* __restrict__ xmT){
    __shared__ float L[11056];
    if (blockIdx.x >= 2*BB_*KK_*CC_/4){
        // ---------------- gemm_mix part ----------------
        int bid = blockIdx.x - 2*BB_*KK_*CC_/4;   // b*256 + o
        int b = bid >> 8, o = bid & 255;
        int t = threadIdx.x;
        const float* hb = h + b*FF_*TT_ + t;
        const float* wr = w_mix + o*FF_;
        float acc = b_mix[o];
        #pragma unroll 8
        for (int f = 0; f < FF_; ++f) acc += wr[f] * hb[f*TT_];
        float v = fmaxf(acc, 0.f);
        xm[bid*TT_ + t] = v;
        xmT[(b*TT_ + t)*FF_ + o] = v;
        return;
    }
    if (threadIdx.x >= 64) return;        // scan uses a single wave; no barriers below
    int sbid = blockIdx.x;
    float* hist = L;              // [8][424] fwd: log trm, idx=160+tau (guard [0,160)); bwd: log w, idx=tau (guard [256,424))
    float* pdL  = L + 8*424;      // [8][168]
    float* EL   = pdL + 8*168;    // [8][204] scaled-linear table (192 used)
    float* PL   = EL + 8*204;     // [8][257]
    float* oL   = PL + 8*257;     // [8][257] fwd: s log staging; bwd: bl staging
    float* fsL  = oL + 8*257;     // [8][36]  init+far sums (linear)
    float* ctL  = fsL + 8*36;     // [8][36]  cross-state factors (linear)
    int lane = threadIdx.x;
    int ch = lane >> 4, r = lane & 15, n = r & 1, q = r >> 1;
    int g = ch*2 + n, go = g ^ 1;
    bool fwd = sbid < (BB_*KK_*CC_/4);
    int gid0 = (fwd ? sbid : sbid - BB_*KK_*CC_/4) * 4;
    int dlim = fwd ? DD_ : (DD_-1);
    for (int idx = lane; idx < 8*168; idx += 64){
        int g2 = idx/168, d2 = idx%168;
        int gg = gid0 + (g2>>1); int c3 = gg % CC_, k3 = (gg/CC_) % KK_;
        pdL[g2*168 + d2] = (d2 < dlim) ? logp_d[((k3*CC_+c3)*2+(g2&1))*DD_ + d2] : -1e30f;
    }
    for (int idx = lane; idx < 4*512; idx += 64){
        int c2 = idx >> 9, j = idx & 511;
        PL[(c2*2 + (j>>8))*257 + (j&255)] = P[(size_t)(gid0+c2)*512 + j];
    }
    int gidc = gid0 + ch; int c = gidc % CC_, k = (gidc/CC_) % KK_;
    const float* Akc = log_A + (k*CC_+c)*4;
    float Epdn[4], Epdf[16];
    #pragma unroll
    for (int i = 0; i < 4; ++i)  Epdn[i] = __expf(pdL[g*168 + q + 8*i]);
    #pragma unroll
    for (int i = 0; i < 16; ++i) Epdf[i] = __expf(pdL[g*168 + 32 + q + 8*i]);

    if (fwd){
        for (int idx = lane; idx < 8*160; idx += 64)
            hist[(idx/160)*424 + (idx%160)] = -1e30f;     // guard below tau=0
        float Aself = Akc[3*n], Across = Akc[2-n];
        float EAs = __expf(Aself);
        float EAc = __expf(Across);
        float llo = log_lo[(k*CC_+c)*2 + n];
        float Etp, pre[4];
        for (int t0 = 0; t0 < TT_; t0 += 32){
            asm volatile("" ::: "memory");
            // Phase A: window max (+init scale), E table, ct factors
            float v[20];
            #pragma unroll
            for (int i = 0; i < 20; ++i) v[i] = hist[g*424 + t0 + q + 8*i];
            float z[10];
            #pragma unroll
            for (int i = 0; i < 10; ++i) z[i] = fmaxf(v[2*i], v[2*i+1]);
            #pragma unroll
            for (int i = 0; i < 5; ++i) z[i] = fmaxf(z[2*i], z[2*i+1]);
            float mt = fmaxf(fmaxf(fmaxf(z[0],z[1]), fmaxf(z[2],z[3])), z[4]);
            mt = dpp_max8(mt);
            float pm = -1e30f;
            #pragma unroll
            for (int j = 0; j < 4; ++j){
                int t = t0 + q + 8*j;
                pm = fmaxf(pm, (t < 168) ? pdL[g*168 + t] : -1e30f);
            }
            pm = dpp_max8(pm);
            mt = fmaxf(mt, llo + pm);          // finite always; scales init <= 1
            #pragma unroll
            for (int i = 0; i < 20; ++i) EL[g*204 + q + 8*i] = __expf(v[i] - mt);
            float mto = dppf<0xB1>(mt);
            #pragma unroll
            for (int j = 0; j < 4; ++j){
                int tt = q + 8*j; int t = t0 + tt;
                float dP = PL[go*257 + t] - PL[g*257 + t];
                ctL[g*36 + tt] = fminf(EAc * __expf(dP + mto - mt), 1e15f);
            }
            asm volatile("" ::: "memory");
            // Phase B: far convolution + init fold
            for (int tt = 0; tt < 32; ++tt){
                float a0 = 0.f, a1 = 0.f;
                #pragma unroll
                for (int i = 0; i < 16; i += 2){
                    a0 = fmaf(EL[g*204 + 127 + tt - q - 8*i],     Epdf[i],   a0);
                    a1 = fmaf(EL[g*204 + 127 + tt - q - 8*(i+1)], Epdf[i+1], a1);
                }
                float a = dpp_sum8(a0 + a1);
                int t = t0 + tt;
                float pdt = (t < 168) ? pdL[g*168 + t] : -1e30f;
                if (r < 2) fsL[g*36 + tt] = a + __expf(llo + pdt - mt);
            }
            asm volatile("" ::: "memory");
            // Phase C: serial, pure linear
            Etp = EL[g*204 + 159];
            #pragma unroll
            for (int i = 0; i < 4; ++i) pre[i] = EL[g*204 + 159 - q - 8*i];
            for (int tt = 0; tt < 32; ++tt){
                int t = t0 + tt;
                float x0 = ((q == 0) ? Etp : pre[0]) * Epdn[0];
                float ac = fmaf(pre[1], Epdn[1], x0);
                ac = fmaf(pre[2], Epdn[2], ac);
                ac = fmaf(pre[3], Epdn[3], ac);
                #pragma unroll
                for (int i = 0; i < 4; ++i) pre[i] = EL[g*204 + 160 + tt - q - 8*i];
                float S = dpp_sum8(ac) + fsL[g*36 + tt];
                S = fminf(fmaxf(S, 1e-30f), 1e15f);
                float So = dppf<0xB1>(S);
                float Et = fminf(fmaf(So, ctL[g*36 + tt], S*EAs), 1e30f);
                float lS = __logf(S), lE = __logf(Et);   // off critical path
                if (r < 2){
                    EL[g*204 + 160 + tt] = Et;
                    hist[g*424 + 160 + t] = lE + mt;
                    oL[g*257 + t] = lS + mt + PL[g*257 + t];
                }
                Etp = Et;
            }
        }
        asm volatile("" ::: "memory");
        for (int idx = lane; idx < 4*512; idx += 64){
            int c2 = idx >> 9, j = idx & 511;
            s_hist[(size_t)(gid0+c2)*512 + j] = oL[(c2*2 + (j>>8))*257 + (j&255)];
        }
        if (r == 0) Zout[gidc] = lse2f(oL[(ch*2)*257 + 255], oL[(ch*2+1)*257 + 255]);
    } else {
        for (int idx = lane; idx < 8*168; idx += 64)
            hist[(idx/168)*424 + 256 + (idx%168)] = -1e30f;  // guard above tau=255
        if (lane < 8){
            hist[lane*424 + 255] = PL[lane*257 + 255];       // w[255] = P[255]
            oL[lane*257 + 255] = 0.f;                        // beta[255] = 0
        }
        float Aown = Akc[3*n], Aoth = Akc[n+1];
        float EAo = __expf(Aown);
        float EAx = __expf(Aoth);
        float Ewp, pre[4];
        for (int t0 = TT_-32; t0 >= 0; t0 -= 32){
            asm volatile("" ::: "memory");
            // Phase A: window [t0+32, t0+191], mw (+seed scale), E table, ct
            float v[20];
            #pragma unroll
            for (int i = 0; i < 20; ++i) v[i] = hist[g*424 + t0 + 32 + q + 8*i];
            float z[10];
            #pragma unroll
            for (int i = 0; i < 10; ++i) z[i] = fmaxf(v[2*i], v[2*i+1]);
            #pragma unroll
            for (int i = 0; i < 5; ++i) z[i] = fmaxf(z[2*i], z[2*i+1]);
            float mw = fmaxf(fmaxf(fmaxf(z[0],z[1]), fmaxf(z[2],z[3])), z[4]);
            mw = dpp_max8(mw);
            mw = fmaxf(mw, PL[g*257 + 255]);   // covers seed scale (first tile)
            #pragma unroll
            for (int i = 0; i < 20; ++i) EL[g*204 + 32 + q + 8*i] = __expf(v[i] - mw);
            float mwo = dppf<0xB1>(mw);
            #pragma unroll
            for (int j = 0; j < 4; ++j){
                int tt = q + 8*j; int t = t0 + tt;
                float dP = PL[g*257 + t] - PL[go*257 + t];   // +P_n - P_o
                ctL[g*36 + tt] = fminf(EAx * __expf(dP + mwo - mw), 1e15f);
            }
            if (t0 == TT_-32 && r < 2)
                EL[g*204 + 31] = __expf(hist[g*424 + 255] - mw);   // seed at idx 31
            asm volatile("" ::: "memory");
            // Phase B: far convolution (j >= 32)
            for (int tt = 0; tt < 32; ++tt){
                float a0 = 0.f, a1 = 0.f;
                #pragma unroll
                for (int i = 0; i < 16; i += 2){
                    a0 = fmaf(EL[g*204 + tt + 33 + q + 8*i],     Epdf[i],   a0);
                    a1 = fmaf(EL[g*204 + tt + 33 + q + 8*(i+1)], Epdf[i+1], a1);
                }
                float a = dpp_sum8(a0 + a1);
                if (r < 2) fsL[g*36 + tt] = a;
            }
            asm volatile("" ::: "memory");
            // Phase C: serial descending, pure linear
            int tts = (t0 == TT_-32) ? 30 : 31;
            Ewp = EL[g*204 + tts + 1];
            #pragma unroll
            for (int i = 0; i < 4; ++i) pre[i] = EL[g*204 + tts + 1 + q + 8*i];
            for (int tt = tts; tt >= 0; --tt){
                int t = t0 + tt;
                float x0 = ((q == 0) ? Ewp : pre[0]) * Epdn[0];
                float ac = fmaf(pre[1], Epdn[1], x0);
                ac = fmaf(pre[2], Epdn[2], ac);
                ac = fmaf(pre[3], Epdn[3], ac);
                #pragma unroll
                for (int i = 0; i < 4; ++i) pre[i] = EL[g*204 + tt + q + 8*i];
                float W = dpp_sum8(ac) + fsL[g*36 + tt];
                W = fminf(fmaxf(W, 1e-30f), 1e15f);
                float Wo = dppf<0xB1>(W);
                float Ewt = fminf(fmaf(Wo, ctL[g*36 + tt], W*EAo), 1e30f);
                float lE = __logf(Ewt);                  // off critical path
                if (r < 2){
                    EL[g*204 + tt] = Ewt;
                    float wt = lE + mw;
                    hist[g*424 + t] = wt;
                    oL[g*257 + t] = wt - PL[g*257 + t];
                }
                Ewp = Ewt;
            }
        }
        asm volatile("" ::: "memory");
        for (int idx = lane; idx < 4*512; idx += 64){
            int c2 = idx >> 9, j = idx & 511;
            beta[(size_t)(gid0+c2)*512 + j] = oL[(c2*2 + (j>>8))*257 + (j&255)];
        }
    }
}

// ---------- 10. logp_event — LDS-staged: block = (b,cc,n,dchunk of 39) ----------
// All per-k slices staged once in ~45 KB LDS; per-output k-loop is LDS-only.
// Arithmetic order per term identical to the previous version (lpz pre-folded).
__global__ __launch_bounds__(256) void k_logpevent(const float* __restrict__ P,
                            const float* __restrict__ s_hist,
                            const float* __restrict__ beta, const float* __restrict__ logp_d,
                            const float* __restrict__ log_lo, const float* __restrict__ log_A,
                            const float* __restrict__ log_pi, const float* __restrict__ Zv,
                            float* __restrict__ out){
    __shared__ float sh0[KK_][TT_];   // s_hist n=0 slice
    __shared__ float sh1[KK_][TT_];   // s_hist n=1 slice
    __shared__ float bet[KK_][TT_];
    __shared__ float Pns[KK_][TT_];
    __shared__ float pds[KK_][256];   // padded to 256 (guard -1e30 for d>=156)
    __shared__ float lpz_s[KK_], llo_s[KK_], lA0[KK_], lA1[KK_];
    int blk = blockIdx.x;             // ((b*CC+cc)*2+n)*4 + dchunk
    int dchunk = blk & 3; int rem = blk >> 2;
    int n = rem & 1; int cc = (rem >> 1) % CC_; int b = rem / (2*CC_);
    int tid = threadIdx.x;
    for (int idx = tid; idx < KK_*TT_; idx += 256){
        int k = idx >> 8, t2 = idx & 255;
        int base2 = (((b*KK_+k)*CC_+cc)*2);
        sh0[k][t2] = s_hist[(size_t)base2*TT_ + t2];
        sh1[k][t2] = s_hist[(size_t)base2*TT_ + TT_ + t2];
        bet[k][t2] = beta[(size_t)(base2 + n)*TT_ + t2];
        Pns[k][t2] = P[(base2 + n)*TT_ + t2];
        int kc = (k*CC_+cc)*2 + n;
        pds[k][t2] = (t2 < DD_) ? logp_d[kc*DD_ + t2] : -1e30f;
    }
    if (tid < KK_){
        int k = tid;
        int kc = (k*CC_+cc)*2 + n;
        lpz_s[k] = log_pi[b*KK_ + k] - Zv[(b*KK_+k)*CC_ + cc];
        llo_s[k] = log_lo[kc];
        lA0[k] = log_A[(k*CC_+cc)*4 + n];
        lA1[k] = log_A[(k*CC_+cc)*4 + 2 + n];
    }
    __syncthreads();
    int t = tid;
    size_t obase = (size_t)(((b*CC_+cc)*2 + n)*DD_)*TT_;
    for (int j = 0; j < 39; ++j){
        int d = dchunk*39 + j;
        int tau = t - 1 - d; int tauc = tau < 0 ? 0 : tau;
        float m = -1e30f, s = 0.f;
        #pragma unroll
        for (int k = 0; k < KK_; ++k){
            float alpha;
            if (d > t){
                alpha = NEGC;
            } else if (d == t){
                alpha = llo_s[k] + pds[k][t] + Pns[k][t];
            } else {
                float u0 = sh0[k][tauc] + lA0[k];
                float u1 = sh1[k][tauc] + lA1[k];
                alpha = lse2_fast(u0, u1) + pds[k][d] + (Pns[k][t] - Pns[k][tauc]);
            }
            lse_acc_fast(m, s, lpz_s[k] + alpha + bet[k][t]);
        }
        out[obase + (size_t)d*TT_ + t] = m + __logf(s);
    }
}

// ---------- 11. lj partials: one block per (bcn, chunk of 39 rows), linear sums ----------
__global__ __launch_bounds__(256) void k_lj(const float* __restrict__ lp_all,
                                            float* __restrict__ ljpart){
    int blk = blockIdx.x;
    int bcn = blk >> 2; int chunk = blk & 3;
    int d0 = chunk * 39;
    const float* lp = lp_all + (size_t)bcn*DD_*TT_;
    int tid = threadIdx.x;
    int wv = tid >> 6; int ln = tid & 63;
    __shared__ float Rp[39][TT_+1];
    for (int rr = wv; rr < 39; rr += 4){
        const float* row = lp + (d0 + rr)*TT_;
        float carry = 0.f;
        if (ln == 0) Rp[rr][0] = 0.f;
        #pragma unroll
        for (int seg = 0; seg < 4; ++seg){
            float v = __expf(fminf(row[seg*64 + ln], 60.f));
            #pragma unroll
            for (int off = 1; off < 64; off <<= 1){
                float u = __shfl_up(v, off);
                if (ln >= off) v += u;
            }
            v += carry;
            Rp[rr][1 + seg*64 + ln] = v;
            carry = __shfl(v, 63);
        }
    }
    __syncthreads();
    float acc = 0.f;
    int t = tid;
    #pragma unroll 4
    for (int rr = 0; rr < 39; ++rr){
        int d = d0 + rr;
        int lo = max(t, d);
        int hi = min(t + d, TT_-1);
        acc += Rp[rr][hi+1] - Rp[rr][lo];
    }
    ljpart[(bcn*4 + chunk)*TT_ + t] = acc;   // linear space
}

// ---------- 12. p_frame from linear partials ----------
__global__ void k_pframe(const float* __restrict__ ljpart, float* __restrict__ out2){
    int idx = blockIdx.x*256 + threadIdx.x;   // (b*C+c)*T + t
    int t = idx & 255; int bc = idx >> 8;
    const float* p0 = ljpart + (size_t)(bc*2 + 0)*4*TT_;
    const float* p1 = ljpart + (size_t)(bc*2 + 1)*4*TT_;
    float s0 = (p0[t] + p0[TT_+t]) + (p0[2*TT_+t] + p0[3*TT_+t]);
    float s1 = (p1[t] + p1[TT_+t]) + (p1[2*TT_+t] + p1[3*TT_+t]);
    float l0 = __logf(fmaxf(s0, 1e-38f));
    float l1 = __logf(fmaxf(s1, 1e-38f));
    float mm = fmaxf(l0, l1);
    float e0 = __expf(l0 - mm), e1 = __expf(l1 - mm);
    out2[idx] = e1 / (e0 + e1);
}

// ---------- launch ----------
extern "C" void kernel_launch(void* const* d_in, const int* in_sizes, int n_in,
                              void* d_out, int out_size, void* d_ws, size_t ws_size,
                              hipStream_t stream){
    const float* h         = (const float*)d_in[0];
    const float* logit_lo1 = (const float*)d_in[1];
    const float* log_A     = (const float*)d_in[2];
    const float* dur_conc  = (const float*)d_in[3];
    const float* dur_rate  = (const float*)d_in[4];
    // d_in[5] dur_mix unused (L=1 -> log_softmax == 0)
    const float* w_mix     = (const float*)d_in[6];
    const float* b_mix     = (const float*)d_in[7];
    const float* q_attn    = (const float*)d_in[8];
    const float* w_attn    = (const float*)d_in[9];
    const float* b_attn    = (const float*)d_in[10];
    const float* w_k       = (const float*)d_in[11];
    const float* b_k       = (const float*)d_in[12];
    const float* bn_gamma  = (const float*)d_in[13];
    const float* bn_beta   = (const float*)d_in[14];
    const float* w_em      = (const float*)d_in[15];
    const float* b_em      = (const float*)d_in[16];

    float* out  = (float*)d_out;                        // logp_event (B,C,N,D,T)
    float* out2 = out + (size_t)BB_*CC_*2*DD_*TT_;      // p_frame (B,C,T)

    // workspace carve (floats) — identical to round 15
    float* ws = (float*)d_ws;
    float* Pbuf   = ws;                 ws += BB_*OO_*TT_;
    float* s_hist = ws;                 ws += BB_*OO_*TT_;
    float* beta   = ws;                 ws += BB_*OO_*TT_;
    float* xbn    = ws;                 ws += BB_*FF_*TT_;
    float* xm     = ws;                 ws += BB_*FF_*TT_;
    float* xmT    = ws;                 ws += BB_*FF_*TT_;
    float* logp_d = ws;                 ws += KK_*CC_*2*DD_;
    float* log_lo = ws;                 ws += KK_*CC_*2;
    float* log_pi = ws;                 ws += BB_*KK_;
    float* Zv     = ws;                 ws += BB_*KK_*CC_;
    float* meanv  = ws;                 ws += FF_;
    float* rstdv  = ws;                 ws += FF_;
    float* ljpart = ws;                 ws += BB_*CC_*2*4*TT_;

    hipLaunchKernelGGL(k_bnstats_logpd, dim3(FF_ + KK_*CC_*2), dim3(256), 0, stream,
                       h, meanv, rstdv, dur_conc, dur_rate, logit_lo1, logp_d, log_lo);
    hipLaunchKernelGGL(k_bnapply,  dim3(BB_*FF_),       dim3(256), 0, stream, h, meanv, rstdv, bn_gamma, bn_beta, xbn);
    hipLaunchKernelGGL(k_gemm_em,  dim3(BB_*10),        dim3(256), 0, stream, xbn, w_em, b_em, Pbuf);
    hipLaunchKernelGGL(k_scan_mix, dim3(2*BB_*KK_*CC_/4 + BB_*FF_), dim3(256), 0, stream,
                       Pbuf, logp_d, log_lo, log_A, s_hist, Zv, beta,
                       h, w_mix, b_mix, xm, xmT);
    hipLaunchKernelGGL(k_attnpool, dim3(BB_),           dim3(256), 0, stream, xm, xmT, q_attn, w_attn, b_attn, w_k, b_k, log_pi);
    hipLaunchKernelGGL(k_logpevent,dim3(BB_*CC_*2*4),   dim3(256), 0, stream, Pbuf, s_hist, beta, logp_d, log_lo, log_A, log_pi, Zv, out);
    hipLaunchKernelGGL(k_lj,       dim3(BB_*CC_*2*4),   dim3(256), 0, stream, out, ljpart);
    hipLaunchKernelGGL(k_pframe,   dim3(BB_*CC_),       dim3(256), 0, stream, ljpart, out2);
}

// Round 17
// 277.683 us; speedup vs baseline: 1.0958x; 1.0958x over previous
//
#include <hip/hip_runtime.h>
#include <math.h>

// Problem constants
#define BB_ 4
#define FF_ 256
#define TT_ 256
#define KK_ 8
#define CC_ 10
#define DD_ 156
#define OO_ 160   // K*C*N
#define NEGC (-1e9f)

// ---------- helpers ----------
__device__ __forceinline__ float softplusf(float x){
    return fmaxf(x, 0.f) + log1pf(expf(-fabsf(x)));
}
__device__ __forceinline__ float lse2f(float a, float b){
    float m = fmaxf(a, b);
    return m + logf(expf(a-m) + expf(b-m));
}
__device__ __forceinline__ float lse2_fast(float a, float b){
    float m = fmaxf(a, b);
    return m + __logf(__expf(a-m) + __expf(b-m));
}
__device__ __forceinline__ void lse_acc(float &m, float &s, float x){
    if (x > m){ s = s*expf(m-x) + 1.f; m = x; }
    else        s += expf(x-m);
}
__device__ __forceinline__ void lse_acc_fast(float &m, float &s, float x){
    if (x > m){ s = s*__expf(m-x) + 1.f; m = x; }
    else        s += __expf(x-m);
}
__device__ __forceinline__ void wave_lse_reduce(float &m, float &s){
    for (int off = 32; off; off >>= 1){
        float m2 = __shfl_xor(m, off);
        float s2 = __shfl_xor(s, off);
        float M  = fmaxf(m, m2);
        s = s*expf(m-M) + s2*expf(m2-M);
        m = M;
    }
}
// DPP move (compile-time ctrl). row_ror:N = 0x120+N; quad_perm[1,0,3,2] = 0xB1.
template<int CTRL>
__device__ __forceinline__ float dppf(float v){
    return __int_as_float(__builtin_amdgcn_update_dpp(
        0, __float_as_int(v), CTRL, 0xF, 0xF, false));
}
__device__ __forceinline__ float dpp_sum8(float a){
    a = a + dppf<0x122>(a);
    a = a + dppf<0x124>(a);
    a = a + dppf<0x128>(a);
    return a;
}
__device__ __forceinline__ float dpp_max8(float a){
    a = fmaxf(a, dppf<0x122>(a));
    a = fmaxf(a, dppf<0x124>(a));
    a = fmaxf(a, dppf<0x128>(a));
    return a;
}

// ---------- 1. bnstats (blocks [0,256)) ∥ logpd (blocks [256,416)) ----------
__global__ void k_bnstats_logpd(const float* __restrict__ h, float* __restrict__ meanv,
                                float* __restrict__ rstdv,
                                const float* __restrict__ conc, const float* __restrict__ rate,
                                const float* __restrict__ logit_lo1, float* __restrict__ logp_d,
                                float* __restrict__ log_lo){
    if (blockIdx.x >= FF_){
        // ---- logpd part (one wave per (k,c,n)) ----
        if (threadIdx.x >= 64) return;
        int kcn = blockIdx.x - FF_;   // (k*C+c)*2+n
        int lane = threadIdx.x;
        float a  = softplusf(conc[kcn]) + 1e-4f;
        float bb = softplusf(rate[kcn]) + 1e-4f;
        float base = a*logf(bb) - lgammaf(a);
        float vals[3]; int ds[3]; int cnt = 0;
        float m = -1e30f, s = 0.f;
        for (int i = 0; i < 3; ++i){
            int d = lane + i*64;
            if (d < DD_){
                float dv = (float)(d+1);
                float x = base + (a - 1.f)*logf(dv) - bb*dv;
                vals[cnt] = x; ds[cnt] = d; ++cnt;
                lse_acc(m, s, x);
            }
        }
        wave_lse_reduce(m, s);
        float total = m + logf(s);
        for (int i = 0; i < cnt; ++i) logp_d[kcn*DD_ + ds[i]] = vals[i] - total;
        if (lane == 0){
            float x = logit_lo1[kcn >> 1];
            float xx = (kcn & 1) ? -x : x;
            log_lo[kcn] = -softplusf(-xx);   // log_sigmoid
        }
        return;
    }
    // ---- bnstats part ----
    int f = blockIdx.x; int tid = threadIdx.x;
    float s = 0.f, s2 = 0.f;
    for (int b = 0; b < BB_; ++b){
        float v = h[(b*FF_ + f)*TT_ + tid];
        s += v; s2 += v*v;
    }
    __shared__ float rs[4], rs2[4];
    for (int off = 32; off; off >>= 1){ s += __shfl_xor(s, off); s2 += __shfl_xor(s2, off); }
    if ((tid & 63) == 0){ rs[tid>>6] = s; rs2[tid>>6] = s2; }
    __syncthreads();
    if (tid == 0){
        float S = rs[0]+rs[1]+rs[2]+rs[3];
        float S2 = rs2[0]+rs2[1]+rs2[2]+rs2[3];
        float mean = S / 1024.f;
        float var = S2 / 1024.f - mean*mean;
        meanv[f] = mean;
        rstdv[f] = rsqrtf(var + 1e-5f);
    }
}

// ---------- 2. bn apply + relu ----------
__global__ void k_bnapply(const float* __restrict__ h, const float* __restrict__ meanv,
                          const float* __restrict__ rstdv, const float* __restrict__ gamma,
                          const float* __restrict__ beta, float* __restrict__ xbn){
    int idx = blockIdx.x*256 + threadIdx.x;           // (b*F+f)*T + t
    int f = (idx >> 8) & 255;
    float x = (h[idx] - meanv[f]) * rstdv[f] * gamma[f] + beta[f];
    xbn[idx] = fmaxf(x, 0.f);
}

// ---------- 3. emission GEMM + fused inclusive prefix over t -> P (r15 version) ----------
__global__ void k_gemm_em(const float* __restrict__ xbn, const float* __restrict__ w_em,
                          const float* __restrict__ b_em, float* __restrict__ Pout){
    int bid = blockIdx.x;                 // b*160 + o
    int b = bid / OO_, o = bid % OO_;
    int t = threadIdx.x;
    const float* xb = xbn + b*FF_*TT_ + t;
    const float* wr = w_em + o*FF_;
    float acc = b_em[o];
    #pragma unroll 8
    for (int f = 0; f < FF_; ++f) acc += wr[f] * xb[f*TT_];
    __shared__ float buf[256];
    buf[t] = acc; __syncthreads();
    for (int off = 1; off < 256; off <<= 1){
        float x = (t >= off) ? buf[t-off] : 0.f;
        __syncthreads();
        buf[t] += x;
        __syncthreads();
    }
    Pout[bid*TT_ + t] = buf[t];
}

// ---------- 5. attention pool -> log_pi (one block per b) ----------
__global__ void k_attnpool(const float* __restrict__ xm, const float* __restrict__ xmT,
                           const float* __restrict__ q,
                           const float* __restrict__ w_attn, const float* __restrict__ b_attn,
                           const float* __restrict__ w_k, const float* __restrict__ b_k,
                           float* __restrict__ log_pi){
    int b = blockIdx.x; int tid = threadIdx.x;
    __shared__ float sc[256], pooled[256], zs[256], red[8];
    const float* xb = xm + b*FF_*TT_;
    float acc = 0.f;
    for (int f = 0; f < FF_; ++f) acc += q[f] * xb[f*TT_ + tid];
    sc[tid] = acc; __syncthreads();
    float v = sc[tid];
    float m = v;
    for (int off = 32; off; off >>= 1) m = fmaxf(m, __shfl_xor(m, off));
    if ((tid & 63) == 0) red[tid>>6] = m;
    __syncthreads();
    m = fmaxf(fmaxf(red[0], red[1]), fmaxf(red[2], red[3]));
    float e = expf(v - m);
    float ssum = e;
    for (int off = 32; off; off >>= 1) ssum += __shfl_xor(ssum, off);
    if ((tid & 63) == 0) red[4 + (tid>>6)] = ssum;
    __syncthreads();
    ssum = red[4]+red[5]+red[6]+red[7];
    __syncthreads();
    sc[tid] = e / ssum; __syncthreads();
    const float* xT = xmT + b*TT_*FF_;
    float pacc = 0.f;
    for (int t2 = 0; t2 < TT_; ++t2) pacc += xT[t2*FF_ + tid] * sc[t2];
    pooled[tid] = pacc; __syncthreads();
    int wv = tid >> 6; int ln = tid & 63;
    for (int ii = 0; ii < 64; ++ii){
        int i = wv*64 + ii;
        float za = 0.f;
        #pragma unroll
        for (int ff = 0; ff < 4; ++ff) za += pooled[ln + 64*ff] * w_attn[i*FF_ + ln + 64*ff];
        for (int off = 32; off; off >>= 1) za += __shfl_xor(za, off);
        if (ln == 0) zs[i] = za + b_attn[i];
    }
    __syncthreads();
    if (wv == 0){
        for (int kk2 = 0; kk2 < KK_; ++kk2){
            float za = 0.f;
            #pragma unroll
            for (int ff = 0; ff < 4; ++ff) za += zs[ln + 64*ff] * w_k[kk2*FF_ + ln + 64*ff];
            for (int off = 32; off; off >>= 1) za += __shfl_xor(za, off);
            if (ln == 0) red[kk2] = za + b_k[kk2];
        }
    }
    __syncthreads();
    if (tid == 0){
        float mm = -1e30f;
        for (int i = 0; i < KK_; ++i) mm = fmaxf(mm, red[i]);
        float su = 0.f;
        for (int i = 0; i < KK_; ++i) su += expf(red[i] - mm);
        sc[0] = mm + logf(su);
    }
    __syncthreads();
    if (tid < KK_) log_pi[b*KK_ + tid] = red[tid] - sc[0];
}

// ---------- 8. MEGA kernel: HSMM scan (blocks [0,160), wave 0 only)
// ∥ mixture GEMM (blocks [160,1184)) — byte-identical to rounds 13-15 ----------
__global__ __launch_bounds__(256) void k_scan_mix(const float* __restrict__ P,
                          const float* __restrict__ logp_d,
                          const float* __restrict__ log_lo, const float* __restrict__ log_A,
                          float* __restrict__ s_hist, float* __restrict__ Zout,
                          float* __restrict__ beta,
                          const float* __restrict__ h, const float* __restrict__ w_mix,
                          const float* __restrict__ b_mix, float* __restrict__ xm,
                          float* __restrict__ xmT){
    __shared__ float L[11056];
    if (blockIdx.x >= 2*BB_*KK_*CC_/4){
        // ---------------- gemm_mix part ----------------
        int bid = blockIdx.x - 2*BB_*KK_*CC_/4;   // b*256 + o
        int b = bid >> 8, o = bid & 255;
        int t = threadIdx.x;
        const float* hb = h + b*FF_*TT_ + t;
        const float* wr = w_mix + o*FF_;
        float acc = b_mix[o];
        #pragma unroll 8
        for (int f = 0; f < FF_; ++f) acc += wr[f] * hb[f*TT_];
        float v = fmaxf(acc, 0.f);
        xm[bid*TT_ + t] = v;
        xmT[(b*TT_ + t)*FF_ + o] = v;
        return;
    }
    if (threadIdx.x >= 64) return;        // scan uses a single wave; no barriers below
    int sbid = blockIdx.x;
    float* hist = L;              // [8][424] fwd: log trm, idx=160+tau (guard [0,160)); bwd: log w, idx=tau (guard [256,424))
    float* pdL  = L + 8*424;      // [8][168]
    float* EL   = pdL + 8*168;    // [8][204] scaled-linear table (192 used)
    float* PL   = EL + 8*204;     // [8][257]
    float* oL   = PL + 8*257;     // [8][257] fwd: s log staging; bwd: bl staging
    float* fsL  = oL + 8*257;     // [8][36]  init+far sums (linear)
    float* ctL  = fsL + 8*36;     // [8][36]  cross-state factors (linear)
    int lane = threadIdx.x;
    int ch = lane >> 4, r = lane & 15, n = r & 1, q = r >> 1;
    int g = ch*2 + n, go = g ^ 1;
    bool fwd = sbid < (BB_*KK_*CC_/4);
    int gid0 = (fwd ? sbid : sbid - BB_*KK_*CC_/4) * 4;
    int dlim = fwd ? DD_ : (DD_-1);
    for (int idx = lane; idx < 8*168; idx += 64){
        int g2 = idx/168, d2 = idx%168;
        int gg = gid0 + (g2>>1); int c3 = gg % CC_, k3 = (gg/CC_) % KK_;
        pdL[g2*168 + d2] = (d2 < dlim) ? logp_d[((k3*CC_+c3)*2+(g2&1))*DD_ + d2] : -1e30f;
    }
    for (int idx = lane; idx < 4*512; idx += 64){
        int c2 = idx >> 9, j = idx & 511;
        PL[(c2*2 + (j>>8))*257 + (j&255)] = P[(size_t)(gid0+c2)*512 + j];
    }
    int gidc = gid0 + ch; int c = gidc % CC_, k = (gidc/CC_) % KK_;
    const float* Akc = log_A + (k*CC_+c)*4;
    float Epdn[4], Epdf[16];
    #pragma unroll
    for (int i = 0; i < 4; ++i)  Epdn[i] = __expf(pdL[g*168 + q + 8*i]);
    #pragma unroll
    for (int i = 0; i < 16; ++i) Epdf[i] = __expf(pdL[g*168 + 32 + q + 8*i]);

    if (fwd){
        for (int idx = lane; idx < 8*160; idx += 64)
            hist[(idx/160)*424 + (idx%160)] = -1e30f;     // guard below tau=0
        float Aself = Akc[3*n], Across = Akc[2-n];
        float EAs = __expf(Aself);
        float EAc = __expf(Across);
        float llo = log_lo[(k*CC_+c)*2 + n];
        float Etp, pre[4];
        for (int t0 = 0; t0 < TT_; t0 += 32){
            asm volatile("" ::: "memory");
            // Phase A: window max (+init scale), E table, ct factors
            float v[20];
            #pragma unroll
            for (int i = 0; i < 20; ++i) v[i] = hist[g*424 + t0 + q + 8*i];
            float z[10];
            #pragma unroll
            for (int i = 0; i < 10; ++i) z[i] = fmaxf(v[2*i], v[2*i+1]);
            #pragma unroll
            for (int i = 0; i < 5; ++i) z[i] = fmaxf(z[2*i], z[2*i+1]);
            float mt = fmaxf(fmaxf(fmaxf(z[0],z[1]), fmaxf(z[2],z[3])), z[4]);
            mt = dpp_max8(mt);
            float pm = -1e30f;
            #pragma unroll
            for (int j = 0; j < 4; ++j){
                int t = t0 + q + 8*j;
                pm = fmaxf(pm, (t < 168) ? pdL[g*168 + t] : -1e30f);
            }
            pm = dpp_max8(pm);
            mt = fmaxf(mt, llo + pm);          // finite always; scales init <= 1
            #pragma unroll
            for (int i = 0; i < 20; ++i) EL[g*204 + q + 8*i] = __expf(v[i] - mt);
            float mto = dppf<0xB1>(mt);
            #pragma unroll
            for (int j = 0; j < 4; ++j){
                int tt = q + 8*j; int t = t0 + tt;
                float dP = PL[go*257 + t] - PL[g*257 + t];
                ctL[g*36 + tt] = fminf(EAc * __expf(dP + mto - mt), 1e15f);
            }
            asm volatile("" ::: "memory");
            // Phase B: far convolution + init fold
            for (int tt = 0; tt < 32; ++tt){
                float a0 = 0.f, a1 = 0.f;
                #pragma unroll
                for (int i = 0; i < 16; i += 2){
                    a0 = fmaf(EL[g*204 + 127 + tt - q - 8*i],     Epdf[i],   a0);
                    a1 = fmaf(EL[g*204 + 127 + tt - q - 8*(i+1)], Epdf[i+1], a1);
                }
                float a = dpp_sum8(a0 + a1);
                int t = t0 + tt;
                float pdt = (t < 168) ? pdL[g*168 + t] : -1e30f;
                if (r < 2) fsL[g*36 + tt] = a + __expf(llo + pdt - mt);
            }
            asm volatile("" ::: "memory");
            // Phase C: serial, pure linear
            Etp = EL[g*204 + 159];
            #pragma unroll
            for (int i = 0; i < 4; ++i) pre[i] = EL[g*204 + 159 - q - 8*i];
            for (int tt = 0; tt < 32; ++tt){
                int t = t0 + tt;
                float x0 = ((q == 0) ? Etp : pre[0]) * Epdn[0];
                float ac = fmaf(pre[1], Epdn[1], x0);
                ac = fmaf(pre[2], Epdn[2], ac);
                ac = fmaf(pre[3], Epdn[3], ac);
                #pragma unroll
                for (int i = 0; i < 4; ++i) pre[i] = EL[g*204 + 160 + tt - q - 8*i];
                float S = dpp_sum8(ac) + fsL[g*36 + tt];
                S = fminf(fmaxf(S, 1e-30f), 1e15f);
                float So = dppf<0xB1>(S);
                float Et = fminf(fmaf(So, ctL[g*36 + tt], S*EAs), 1e30f);
                float lS = __logf(S), lE = __logf(Et);   // off critical path
                if (r < 2){
                    EL[g*204 + 160 + tt] = Et;
                    hist[g*424 + 160 + t] = lE + mt;
                    oL[g*257 + t] = lS + mt + PL[g*257 + t];
                }
                Etp = Et;
            }
        }
        asm volatile("" ::: "memory");
        for (int idx = lane; idx < 4*512; idx += 64){
            int c2 = idx >> 9, j = idx & 511;
            s_hist[(size_t)(gid0+c2)*512 + j] = oL[(c2*2 + (j>>8))*257 + (j&255)];
        }
        if (r == 0) Zout[gidc] = lse2f(oL[(ch*2)*257 + 255], oL[(ch*2+1)*257 + 255]);
    } else {
        for (int idx = lane; idx < 8*168; idx += 64)
            hist[(idx/168)*424 + 256 + (idx%168)] = -1e30f;  // guard above tau=255
        if (lane < 8){
            hist[lane*424 + 255] = PL[lane*257 + 255];       // w[255] = P[255]
            oL[lane*257 + 255] = 0.f;                        // beta[255] = 0
        }
        float Aown = Akc[3*n], Aoth = Akc[n+1];
        float EAo = __expf(Aown);
        float EAx = __expf(Aoth);
        float Ewp, pre[4];
        for (int t0 = TT_-32; t0 >= 0; t0 -= 32){
            asm volatile("" ::: "memory");
            // Phase A: window [t0+32, t0+191], mw (+seed scale), E table, ct
            float v[20];
            #pragma unroll
            for (int i = 0; i < 20; ++i) v[i] = hist[g*424 + t0 + 32 + q + 8*i];
            float z[10];
            #pragma unroll
            for (int i = 0; i < 10; ++i) z[i] = fmaxf(v[2*i], v[2*i+1]);
            #pragma unroll
            for (int i = 0; i < 5; ++i) z[i] = fmaxf(z[2*i], z[2*i+1]);
            float mw = fmaxf(fmaxf(fmaxf(z[0],z[1]), fmaxf(z[2],z[3])), z[4]);
            mw = dpp_max8(mw);
            mw = fmaxf(mw, PL[g*257 + 255]);   // covers seed scale (first tile)
            #pragma unroll
            for (int i = 0; i < 20; ++i) EL[g*204 + 32 + q + 8*i] = __expf(v[i] - mw);
            float mwo = dppf<0xB1>(mw);
            #pragma unroll
            for (int j = 0; j < 4; ++j){
                int tt = q + 8*j; int t = t0 + tt;
                float dP = PL[g*257 + t] - PL[go*257 + t];   // +P_n - P_o
                ctL[g*36 + tt] = fminf(EAx * __expf(dP + mwo - mw), 1e15f);
            }
            if (t0 == TT_-32 && r < 2)
                EL[g*204 + 31] = __expf(hist[g*424 + 255] - mw);   // seed at idx 31
            asm volatile("" ::: "memory");
            // Phase B: far convolution (j >= 32)
            for (int tt = 0; tt < 32; ++tt){
                float a0 = 0.f, a1 = 0.f;
                #pragma unroll
                for (int i = 0; i < 16; i += 2){
                    a0 = fmaf(EL[g*204 + tt + 33 + q + 8*i],     Epdf[i],   a0);
                    a1 = fmaf(EL[g*204 + tt + 33 + q + 8*(i+1)], Epdf[i+1], a1);
                }
                float a = dpp_sum8(a0 + a1);
                if (r < 2) fsL[g*36 + tt] = a;
            }
            asm volatile("" ::: "memory");
            // Phase C: serial descending, pure linear
            int tts = (t0 == TT_-32) ? 30 : 31;
            Ewp = EL[g*204 + tts + 1];
            #pragma unroll
            for (int i = 0; i < 4; ++i) pre[i] = EL[g*204 + tts + 1 + q + 8*i];
            for (int tt = tts; tt >= 0; --tt){
                int t = t0 + tt;
                float x0 = ((q == 0) ? Ewp : pre[0]) * Epdn[0];
                float ac = fmaf(pre[1], Epdn[1], x0);
                ac = fmaf(pre[2], Epdn[2], ac);
                ac = fmaf(pre[3], Epdn[3], ac);
                #pragma unroll
                for (int i = 0; i < 4; ++i) pre[i] = EL[g*204 + tt + q + 8*i];
                float W = dpp_sum8(ac) + fsL[g*36 + tt];
                W = fminf(fmaxf(W, 1e-30f), 1e15f);
                float Wo = dppf<0xB1>(W);
                float Ewt = fminf(fmaf(Wo, ctL[g*36 + tt], W*EAo), 1e30f);
                float lE = __logf(Ewt);                  // off critical path
                if (r < 2){
                    EL[g*204 + tt] = Ewt;
                    float wt = lE + mw;
                    hist[g*424 + t] = wt;
                    oL[g*257 + t] = wt - PL[g*257 + t];
                }
                Ewp = Ewt;
            }
        }
        asm volatile("" ::: "memory");
        for (int idx = lane; idx < 4*512; idx += 64){
            int c2 = idx >> 9, j = idx & 511;
            beta[(size_t)(gid0+c2)*512 + j] = oL[(c2*2 + (j>>8))*257 + (j&255)];
        }
    }
}

// ---------- 10. logp_event — LDS-staged: block = (b,cc,n,dchunk of 39) ----------
// THE ONLY DELTA vs round 15. All per-k slices staged once in ~41 KB LDS;
// per-output k-loop is LDS-only. Arithmetic per term identical to r15.
__global__ __launch_bounds__(256) void k_logpevent(const float* __restrict__ P,
                            const float* __restrict__ s_hist,
                            const float* __restrict__ beta, const float* __restrict__ logp_d,
                            const float* __restrict__ log_lo, const float* __restrict__ log_A,
                            const float* __restrict__ log_pi, const float* __restrict__ Zv,
                            float* __restrict__ out){
    __shared__ float sh0[KK_][TT_];   // s_hist n=0 slice
    __shared__ float sh1[KK_][TT_];   // s_hist n=1 slice
    __shared__ float bet[KK_][TT_];
    __shared__ float Pns[KK_][TT_];
    __shared__ float pds[KK_][256];   // padded to 256 (guard -1e30 for d>=156)
    __shared__ float lpz_s[KK_], llo_s[KK_], lA0[KK_], lA1[KK_];
    int blk = blockIdx.x;             // ((b*CC+cc)*2+n)*4 + dchunk
    int dchunk = blk & 3; int rem = blk >> 2;
    int n = rem & 1; int cc = (rem >> 1) % CC_; int b = rem / (2*CC_);
    int tid = threadIdx.x;
    for (int idx = tid; idx < KK_*TT_; idx += 256){
        int k = idx >> 8, t2 = idx & 255;
        int base2 = (((b*KK_+k)*CC_+cc)*2);
        sh0[k][t2] = s_hist[(size_t)base2*TT_ + t2];
        sh1[k][t2] = s_hist[(size_t)base2*TT_ + TT_ + t2];
        bet[k][t2] = beta[(size_t)(base2 + n)*TT_ + t2];
        Pns[k][t2] = P[(base2 + n)*TT_ + t2];
        int kc = (k*CC_+cc)*2 + n;
        pds[k][t2] = (t2 < DD_) ? logp_d[kc*DD_ + t2] : -1e30f;
    }
    if (tid < KK_){
        int k = tid;
        int kc = (k*CC_+cc)*2 + n;
        lpz_s[k] = log_pi[b*KK_ + k] - Zv[(b*KK_+k)*CC_ + cc];
        llo_s[k] = log_lo[kc];
        lA0[k] = log_A[(k*CC_+cc)*4 + n];
        lA1[k] = log_A[(k*CC_+cc)*4 + 2 + n];
    }
    __syncthreads();
    int t = tid;
    size_t obase = (size_t)(((b*CC_+cc)*2 + n)*DD_)*TT_;
    for (int j = 0; j < 39; ++j){
        int d = dchunk*39 + j;
        int tau = t - 1 - d; int tauc = tau < 0 ? 0 : tau;
        float m = -1e30f, s = 0.f;
        #pragma unroll
        for (int k = 0; k < KK_; ++k){
            float alpha;
            if (d > t){
                alpha = NEGC;
            } else if (d == t){
                alpha = llo_s[k] + pds[k][t] + Pns[k][t];
            } else {
                float u0 = sh0[k][tauc] + lA0[k];
                float u1 = sh1[k][tauc] + lA1[k];
                alpha = lse2_fast(u0, u1) + pds[k][d] + (Pns[k][t] - Pns[k][tauc]);
            }
            lse_acc_fast(m, s, lpz_s[k] + alpha + bet[k][t]);
        }
        out[obase + (size_t)d*TT_ + t] = m + __logf(s);
    }
}

// ---------- 11. lj partials: one block per (bcn, chunk of 39 rows), linear sums ----------
__global__ __launch_bounds__(256) void k_lj(const float* __restrict__ lp_all,
                                            float* __restrict__ ljpart){
    int blk = blockIdx.x;
    int bcn = blk >> 2; int chunk = blk & 3;
    int d0 = chunk * 39;
    const float* lp = lp_all + (size_t)bcn*DD_*TT_;
    int tid = threadIdx.x;
    int wv = tid >> 6; int ln = tid & 63;
    __shared__ float Rp[39][TT_+1];
    for (int rr = wv; rr < 39; rr += 4){
        const float* row = lp + (d0 + rr)*TT_;
        float carry = 0.f;
        if (ln == 0) Rp[rr][0] = 0.f;
        #pragma unroll
        for (int seg = 0; seg < 4; ++seg){
            float v = __expf(fminf(row[seg*64 + ln], 60.f));
            #pragma unroll
            for (int off = 1; off < 64; off <<= 1){
                float u = __shfl_up(v, off);
                if (ln >= off) v += u;
            }
            v += carry;
            Rp[rr][1 + seg*64 + ln] = v;
            carry = __shfl(v, 63);
        }
    }
    __syncthreads();
    float acc = 0.f;
    int t = tid;
    #pragma unroll 4
    for (int rr = 0; rr < 39; ++rr){
        int d = d0 + rr;
        int lo = max(t, d);
        int hi = min(t + d, TT_-1);
        acc += Rp[rr][hi+1] - Rp[rr][lo];
    }
    ljpart[(bcn*4 + chunk)*TT_ + t] = acc;   // linear space
}

// ---------- 12. p_frame from linear partials ----------
__global__ void k_pframe(const float* __restrict__ ljpart, float* __restrict__ out2){
    int idx = blockIdx.x*256 + threadIdx.x;   // (b*C+c)*T + t
    int t = idx & 255; int bc = idx >> 8;
    const float* p0 = ljpart + (size_t)(bc*2 + 0)*4*TT_;
    const float* p1 = ljpart + (size_t)(bc*2 + 1)*4*TT_;
    float s0 = (p0[t] + p0[TT_+t]) + (p0[2*TT_+t] + p0[3*TT_+t]);
    float s1 = (p1[t] + p1[TT_+t]) + (p1[2*TT_+t] + p1[3*TT_+t]);
    float l0 = __logf(fmaxf(s0, 1e-38f));
    float l1 = __logf(fmaxf(s1, 1e-38f));
    float mm = fmaxf(l0, l1);
    float e0 = __expf(l0 - mm), e1 = __expf(l1 - mm);
    out2[idx] = e1 / (e0 + e1);
}

// ---------- launch ----------
extern "C" void kernel_launch(void* const* d_in, const int* in_sizes, int n_in,
                              void* d_out, int out_size, void* d_ws, size_t ws_size,
                              hipStream_t stream){
    const float* h         = (const float*)d_in[0];
    const float* logit_lo1 = (const float*)d_in[1];
    const float* log_A     = (const float*)d_in[2];
    const float* dur_conc  = (const float*)d_in[3];
    const float* dur_rate  = (const float*)d_in[4];
    // d_in[5] dur_mix unused (L=1 -> log_softmax == 0)
    const float* w_mix     = (const float*)d_in[6];
    const float* b_mix     = (const float*)d_in[7];
    const float* q_attn    = (const float*)d_in[8];
    const float* w_attn    = (const float*)d_in[9];
    const float* b_attn    = (const float*)d_in[10];
    const float* w_k       = (const float*)d_in[11];
    const float* b_k       = (const float*)d_in[12];
    const float* bn_gamma  = (const float*)d_in[13];
    const float* bn_beta   = (const float*)d_in[14];
    const float* w_em      = (const float*)d_in[15];
    const float* b_em      = (const float*)d_in[16];

    float* out  = (float*)d_out;                        // logp_event (B,C,N,D,T)
    float* out2 = out + (size_t)BB_*CC_*2*DD_*TT_;      // p_frame (B,C,T)

    // workspace carve (floats) — identical to round 15
    float* ws = (float*)d_ws;
    float* Pbuf   = ws;                 ws += BB_*OO_*TT_;
    float* s_hist = ws;                 ws += BB_*OO_*TT_;
    float* beta   = ws;                 ws += BB_*OO_*TT_;
    float* xbn    = ws;                 ws += BB_*FF_*TT_;
    float* xm     = ws;                 ws += BB_*FF_*TT_;
    float* xmT    = ws;                 ws += BB_*FF_*TT_;
    float* logp_d = ws;                 ws += KK_*CC_*2*DD_;
    float* log_lo = ws;                 ws += KK_*CC_*2;
    float* log_pi = ws;                 ws += BB_*KK_;
    float* Zv     = ws;                 ws += BB_*KK_*CC_;
    float* meanv  = ws;                 ws += FF_;
    float* rstdv  = ws;                 ws += FF_;
    float* ljpart = ws;                 ws += BB_*CC_*2*4*TT_;

    hipLaunchKernelGGL(k_bnstats_logpd, dim3(FF_ + KK_*CC_*2), dim3(256), 0, stream,
                       h, meanv, rstdv, dur_conc, dur_rate, logit_lo1, logp_d, log_lo);
    hipLaunchKernelGGL(k_bnapply,  dim3(BB_*FF_),       dim3(256), 0, stream, h, meanv, rstdv, bn_gamma, bn_beta, xbn);
    hipLaunchKernelGGL(k_gemm_em,  dim3(BB_*OO_),       dim3(256), 0, stream, xbn, w_em, b_em, Pbuf);
    hipLaunchKernelGGL(k_scan_mix, dim3(2*BB_*KK_*CC_/4 + BB_*FF_), dim3(256), 0, stream,
                       Pbuf, logp_d, log_lo, log_A, s_hist, Zv, beta,
                       h, w_mix, b_mix, xm, xmT);
    hipLaunchKernelGGL(k_attnpool, dim3(BB_),           dim3(256), 0, stream, xm, xmT, q_attn, w_attn, b_attn, w_k, b_k, log_pi);
    hipLaunchKernelGGL(k_logpevent,dim3(BB_*CC_*2*4),   dim3(256), 0, stream, Pbuf, s_hist, beta, logp_d, log_lo, log_A, log_pi, Zv, out);
    hipLaunchKernelGGL(k_lj,       dim3(BB_*CC_*2*4),   dim3(256), 0, stream, out, ljpart);
    hipLaunchKernelGGL(k_pframe,   dim3(BB_*CC_),       dim3(256), 0, stream, ljpart, out2);
}

// Round 18
// 247.620 us; speedup vs baseline: 1.2289x; 1.1214x over previous
//
#include <hip/hip_runtime.h>
#include <math.h>

// Problem constants
#define BB_ 4
#define FF_ 256
#define TT_ 256
#define KK_ 8
#define CC_ 10
#define DD_ 156
#define OO_ 160   // K*C*N
#define NEGC (-1e9f)

// ---------- helpers ----------
__device__ __forceinline__ float softplusf(float x){
    return fmaxf(x, 0.f) + log1pf(expf(-fabsf(x)));
}
__device__ __forceinline__ float lse2f(float a, float b){
    float m = fmaxf(a, b);
    return m + logf(expf(a-m) + expf(b-m));
}
__device__ __forceinline__ float lse2_fast(float a, float b){
    float m = fmaxf(a, b);
    return m + __logf(__expf(a-m) + __expf(b-m));
}
__device__ __forceinline__ void lse_acc(float &m, float &s, float x){
    if (x > m){ s = s*expf(m-x) + 1.f; m = x; }
    else        s += expf(x-m);
}
__device__ __forceinline__ void lse_acc_fast(float &m, float &s, float x){
    if (x > m){ s = s*__expf(m-x) + 1.f; m = x; }
    else        s += __expf(x-m);
}
__device__ __forceinline__ void wave_lse_reduce(float &m, float &s){
    for (int off = 32; off; off >>= 1){
        float m2 = __shfl_xor(m, off);
        float s2 = __shfl_xor(s, off);
        float M  = fmaxf(m, m2);
        s = s*expf(m-M) + s2*expf(m2-M);
        m = M;
    }
}
// DPP move (compile-time ctrl). row_ror:N = 0x120+N; quad_perm[1,0,3,2] = 0xB1.
template<int CTRL>
__device__ __forceinline__ float dppf(float v){
    return __int_as_float(__builtin_amdgcn_update_dpp(
        0, __float_as_int(v), CTRL, 0xF, 0xF, false));
}
__device__ __forceinline__ float dpp_sum8(float a){
    a = a + dppf<0x122>(a);
    a = a + dppf<0x124>(a);
    a = a + dppf<0x128>(a);
    return a;
}
__device__ __forceinline__ float dpp_max8(float a){
    a = fmaxf(a, dppf<0x122>(a));
    a = fmaxf(a, dppf<0x124>(a));
    a = fmaxf(a, dppf<0x128>(a));
    return a;
}

// ---------- 1. bnstats (blocks [0,256)) ∥ logpd (blocks [256,416)) ----------
__global__ void k_bnstats_logpd(const float* __restrict__ h, float* __restrict__ meanv,
                                float* __restrict__ rstdv,
                                const float* __restrict__ conc, const float* __restrict__ rate,
                                const float* __restrict__ logit_lo1, float* __restrict__ logp_d,
                                float* __restrict__ log_lo){
    if (blockIdx.x >= FF_){
        // ---- logpd part (one wave per (k,c,n)) ----
        if (threadIdx.x >= 64) return;
        int kcn = blockIdx.x - FF_;   // (k*C+c)*2+n
        int lane = threadIdx.x;
        float a  = softplusf(conc[kcn]) + 1e-4f;
        float bb = softplusf(rate[kcn]) + 1e-4f;
        float base = a*logf(bb) - lgammaf(a);
        float vals[3]; int ds[3]; int cnt = 0;
        float m = -1e30f, s = 0.f;
        for (int i = 0; i < 3; ++i){
            int d = lane + i*64;
            if (d < DD_){
                float dv = (float)(d+1);
                float x = base + (a - 1.f)*logf(dv) - bb*dv;
                vals[cnt] = x; ds[cnt] = d; ++cnt;
                lse_acc(m, s, x);
            }
        }
        wave_lse_reduce(m, s);
        float total = m + logf(s);
        for (int i = 0; i < cnt; ++i) logp_d[kcn*DD_ + ds[i]] = vals[i] - total;
        if (lane == 0){
            float x = logit_lo1[kcn >> 1];
            float xx = (kcn & 1) ? -x : x;
            log_lo[kcn] = -softplusf(-xx);   // log_sigmoid
        }
        return;
    }
    // ---- bnstats part ----
    int f = blockIdx.x; int tid = threadIdx.x;
    float s = 0.f, s2 = 0.f;
    for (int b = 0; b < BB_; ++b){
        float v = h[(b*FF_ + f)*TT_ + tid];
        s += v; s2 += v*v;
    }
    __shared__ float rs[4], rs2[4];
    for (int off = 32; off; off >>= 1){ s += __shfl_xor(s, off); s2 += __shfl_xor(s2, off); }
    if ((tid & 63) == 0){ rs[tid>>6] = s; rs2[tid>>6] = s2; }
    __syncthreads();
    if (tid == 0){
        float S = rs[0]+rs[1]+rs[2]+rs[3];
        float S2 = rs2[0]+rs2[1]+rs2[2]+rs2[3];
        float mean = S / 1024.f;
        float var = S2 / 1024.f - mean*mean;
        meanv[f] = mean;
        rstdv[f] = rsqrtf(var + 1e-5f);
    }
}

// ---------- 2. bn apply + relu ----------
__global__ void k_bnapply(const float* __restrict__ h, const float* __restrict__ meanv,
                          const float* __restrict__ rstdv, const float* __restrict__ gamma,
                          const float* __restrict__ beta, float* __restrict__ xbn){
    int idx = blockIdx.x*256 + threadIdx.x;           // (b*F+f)*T + t
    int f = (idx >> 8) & 255;
    float x = (h[idx] - meanv[f]) * rstdv[f] * gamma[f] + beta[f];
    xbn[idx] = fmaxf(x, 0.f);
}

// ---------- 3. emission GEMM + fused inclusive prefix over t -> P ----------
__global__ void k_gemm_em(const float* __restrict__ xbn, const float* __restrict__ w_em,
                          const float* __restrict__ b_em, float* __restrict__ Pout){
    int bid = blockIdx.x;                 // b*160 + o
    int b = bid / OO_, o = bid % OO_;
    int t = threadIdx.x;
    const float* xb = xbn + b*FF_*TT_ + t;
    const float* wr = w_em + o*FF_;
    float acc = b_em[o];
    #pragma unroll 8
    for (int f = 0; f < FF_; ++f) acc += wr[f] * xb[f*TT_];
    __shared__ float buf[256];
    buf[t] = acc; __syncthreads();
    for (int off = 1; off < 256; off <<= 1){
        float x = (t >= off) ? buf[t-off] : 0.f;
        __syncthreads();
        buf[t] += x;
        __syncthreads();
    }
    Pout[bid*TT_ + t] = buf[t];
}

// ---------- 5. attention pool -> log_pi (one block per b) ----------
__global__ void k_attnpool(const float* __restrict__ xm, const float* __restrict__ xmT,
                           const float* __restrict__ q,
                           const float* __restrict__ w_attn, const float* __restrict__ b_attn,
                           const float* __restrict__ w_k, const float* __restrict__ b_k,
                           float* __restrict__ log_pi){
    int b = blockIdx.x; int tid = threadIdx.x;
    __shared__ float sc[256], pooled[256], zs[256], red[8];
    const float* xb = xm + b*FF_*TT_;
    float acc = 0.f;
    for (int f = 0; f < FF_; ++f) acc += q[f] * xb[f*TT_ + tid];
    sc[tid] = acc; __syncthreads();
    float v = sc[tid];
    float m = v;
    for (int off = 32; off; off >>= 1) m = fmaxf(m, __shfl_xor(m, off));
    if ((tid & 63) == 0) red[tid>>6] = m;
    __syncthreads();
    m = fmaxf(fmaxf(red[0], red[1]), fmaxf(red[2], red[3]));
    float e = expf(v - m);
    float ssum = e;
    for (int off = 32; off; off >>= 1) ssum += __shfl_xor(ssum, off);
    if ((tid & 63) == 0) red[4 + (tid>>6)] = ssum;
    __syncthreads();
    ssum = red[4]+red[5]+red[6]+red[7];
    __syncthreads();
    sc[tid] = e / ssum; __syncthreads();
    const float* xT = xmT + b*TT_*FF_;
    float pacc = 0.f;
    for (int t2 = 0; t2 < TT_; ++t2) pacc += xT[t2*FF_ + tid] * sc[t2];
    pooled[tid] = pacc; __syncthreads();
    int wv = tid >> 6; int ln = tid & 63;
    for (int ii = 0; ii < 64; ++ii){
        int i = wv*64 + ii;
        float za = 0.f;
        #pragma unroll
        for (int ff = 0; ff < 4; ++ff) za += pooled[ln + 64*ff] * w_attn[i*FF_ + ln + 64*ff];
        for (int off = 32; off; off >>= 1) za += __shfl_xor(za, off);
        if (ln == 0) zs[i] = za + b_attn[i];
    }
    __syncthreads();
    if (wv == 0){
        for (int kk2 = 0; kk2 < KK_; ++kk2){
            float za = 0.f;
            #pragma unroll
            for (int ff = 0; ff < 4; ++ff) za += zs[ln + 64*ff] * w_k[kk2*FF_ + ln + 64*ff];
            for (int off = 32; off; off >>= 1) za += __shfl_xor(za, off);
            if (ln == 0) red[kk2] = za + b_k[kk2];
        }
    }
    __syncthreads();
    if (tid == 0){
        float mm = -1e30f;
        for (int i = 0; i < KK_; ++i) mm = fmaxf(mm, red[i]);
        float su = 0.f;
        for (int i = 0; i < KK_; ++i) su += expf(red[i] - mm);
        sc[0] = mm + logf(su);
    }
    __syncthreads();
    if (tid < KK_) log_pi[b*KK_ + tid] = red[tid] - sc[0];
}

// ---------- 8. MEGA kernel: HSMM scan (blocks [0,160), wave 0 only)
// ∥ mixture GEMM (blocks [160,1184)).
// ONLY delta vs r15: bank-conflict padding hist 424->428, pdL 168->172
// (both ≡12 mod 32; pure layout change, guard fill identical).
__global__ __launch_bounds__(256) void k_scan_mix(const float* __restrict__ P,
                          const float* __restrict__ logp_d,
                          const float* __restrict__ log_lo, const float* __restrict__ log_A,
                          float* __restrict__ s_hist, float* __restrict__ Zout,
                          float* __restrict__ beta,
                          const float* __restrict__ h, const float* __restrict__ w_mix,
                          const float* __restrict__ b_mix, float* __restrict__ xm,
                          float* __restrict__ xmT){
    __shared__ float L[11120];
    if (blockIdx.x >= 2*BB_*KK_*CC_/4){
        // ---------------- gemm_mix part ----------------
        int bid = blockIdx.x - 2*BB_*KK_*CC_/4;   // b*256 + o
        int b = bid >> 8, o = bid & 255;
        int t = threadIdx.x;
        const float* hb = h + b*FF_*TT_ + t;
        const float* wr = w_mix + o*FF_;
        float acc = b_mix[o];
        #pragma unroll 8
        for (int f = 0; f < FF_; ++f) acc += wr[f] * hb[f*TT_];
        float v = fmaxf(acc, 0.f);
        xm[bid*TT_ + t] = v;
        xmT[(b*TT_ + t)*FF_ + o] = v;
        return;
    }
    if (threadIdx.x >= 64) return;        // scan uses a single wave; no barriers below
    int sbid = blockIdx.x;
    float* hist = L;              // [8][428] fwd: log trm, idx=160+tau (guard [0,160)); bwd: log w, idx=tau (guard [256,428))
    float* pdL  = L + 8*428;      // [8][172]
    float* EL   = pdL + 8*172;    // [8][204] scaled-linear table (192 used)
    float* PL   = EL + 8*204;     // [8][257]
    float* oL   = PL + 8*257;     // [8][257] fwd: s log staging; bwd: bl staging
    float* fsL  = oL + 8*257;     // [8][36]  init+far sums (linear)
    float* ctL  = fsL + 8*36;     // [8][36]  cross-state factors (linear)
    int lane = threadIdx.x;
    int ch = lane >> 4, r = lane & 15, n = r & 1, q = r >> 1;
    int g = ch*2 + n, go = g ^ 1;
    bool fwd = sbid < (BB_*KK_*CC_/4);
    int gid0 = (fwd ? sbid : sbid - BB_*KK_*CC_/4) * 4;
    int dlim = fwd ? DD_ : (DD_-1);
    for (int idx = lane; idx < 8*172; idx += 64){
        int g2 = idx/172, d2 = idx%172;
        int gg = gid0 + (g2>>1); int c3 = gg % CC_, k3 = (gg/CC_) % KK_;
        pdL[g2*172 + d2] = (d2 < dlim) ? logp_d[((k3*CC_+c3)*2+(g2&1))*DD_ + d2] : -1e30f;
    }
    for (int idx = lane; idx < 4*512; idx += 64){
        int c2 = idx >> 9, j = idx & 511;
        PL[(c2*2 + (j>>8))*257 + (j&255)] = P[(size_t)(gid0+c2)*512 + j];
    }
    int gidc = gid0 + ch; int c = gidc % CC_, k = (gidc/CC_) % KK_;
    const float* Akc = log_A + (k*CC_+c)*4;
    float Epdn[4], Epdf[16];
    #pragma unroll
    for (int i = 0; i < 4; ++i)  Epdn[i] = __expf(pdL[g*172 + q + 8*i]);
    #pragma unroll
    for (int i = 0; i < 16; ++i) Epdf[i] = __expf(pdL[g*172 + 32 + q + 8*i]);

    if (fwd){
        for (int idx = lane; idx < 8*160; idx += 64)
            hist[(idx/160)*428 + (idx%160)] = -1e30f;     // guard below tau=0
        float Aself = Akc[3*n], Across = Akc[2-n];
        float EAs = __expf(Aself);
        float EAc = __expf(Across);
        float llo = log_lo[(k*CC_+c)*2 + n];
        float Etp, pre[4];
        for (int t0 = 0; t0 < TT_; t0 += 32){
            asm volatile("" ::: "memory");
            // Phase A: window max (+init scale), E table, ct factors
            float v[20];
            #pragma unroll
            for (int i = 0; i < 20; ++i) v[i] = hist[g*428 + t0 + q + 8*i];
            float z[10];
            #pragma unroll
            for (int i = 0; i < 10; ++i) z[i] = fmaxf(v[2*i], v[2*i+1]);
            #pragma unroll
            for (int i = 0; i < 5; ++i) z[i] = fmaxf(z[2*i], z[2*i+1]);
            float mt = fmaxf(fmaxf(fmaxf(z[0],z[1]), fmaxf(z[2],z[3])), z[4]);
            mt = dpp_max8(mt);
            float pm = -1e30f;
            #pragma unroll
            for (int j = 0; j < 4; ++j){
                int t = t0 + q + 8*j;
                pm = fmaxf(pm, (t < 172) ? pdL[g*172 + t] : -1e30f);
            }
            pm = dpp_max8(pm);
            mt = fmaxf(mt, llo + pm);          // finite always; scales init <= 1
            #pragma unroll
            for (int i = 0; i < 20; ++i) EL[g*204 + q + 8*i] = __expf(v[i] - mt);
            float mto = dppf<0xB1>(mt);
            #pragma unroll
            for (int j = 0; j < 4; ++j){
                int tt = q + 8*j; int t = t0 + tt;
                float dP = PL[go*257 + t] - PL[g*257 + t];
                ctL[g*36 + tt] = fminf(EAc * __expf(dP + mto - mt), 1e15f);
            }
            asm volatile("" ::: "memory");
            // Phase B: far convolution + init fold
            for (int tt = 0; tt < 32; ++tt){
                float a0 = 0.f, a1 = 0.f;
                #pragma unroll
                for (int i = 0; i < 16; i += 2){
                    a0 = fmaf(EL[g*204 + 127 + tt - q - 8*i],     Epdf[i],   a0);
                    a1 = fmaf(EL[g*204 + 127 + tt - q - 8*(i+1)], Epdf[i+1], a1);
                }
                float a = dpp_sum8(a0 + a1);
                int t = t0 + tt;
                float pdt = (t < 172) ? pdL[g*172 + t] : -1e30f;
                if (r < 2) fsL[g*36 + tt] = a + __expf(llo + pdt - mt);
            }
            asm volatile("" ::: "memory");
            // Phase C: serial, pure linear
            Etp = EL[g*204 + 159];
            #pragma unroll
            for (int i = 0; i < 4; ++i) pre[i] = EL[g*204 + 159 - q - 8*i];
            for (int tt = 0; tt < 32; ++tt){
                int t = t0 + tt;
                float x0 = ((q == 0) ? Etp : pre[0]) * Epdn[0];
                float ac = fmaf(pre[1], Epdn[1], x0);
                ac = fmaf(pre[2], Epdn[2], ac);
                ac = fmaf(pre[3], Epdn[3], ac);
                #pragma unroll
                for (int i = 0; i < 4; ++i) pre[i] = EL[g*204 + 160 + tt - q - 8*i];
                float S = dpp_sum8(ac) + fsL[g*36 + tt];
                S = fminf(fmaxf(S, 1e-30f), 1e15f);
                float So = dppf<0xB1>(S);
                float Et = fminf(fmaf(So, ctL[g*36 + tt], S*EAs), 1e30f);
                float lS = __logf(S), lE = __logf(Et);   // off critical path
                if (r < 2){
                    EL[g*204 + 160 + tt] = Et;
                    hist[g*428 + 160 + t] = lE + mt;
                    oL[g*257 + t] = lS + mt + PL[g*257 + t];
                }
                Etp = Et;
            }
        }
        asm volatile("" ::: "memory");
        for (int idx = lane; idx < 4*512; idx += 64){
            int c2 = idx >> 9, j = idx & 511;
            s_hist[(size_t)(gid0+c2)*512 + j] = oL[(c2*2 + (j>>8))*257 + (j&255)];
        }
        if (r == 0) Zout[gidc] = lse2f(oL[(ch*2)*257 + 255], oL[(ch*2+1)*257 + 255]);
    } else {
        for (int idx = lane; idx < 8*172; idx += 64)
            hist[(idx/172)*428 + 256 + (idx%172)] = -1e30f;  // guard above tau=255
        if (lane < 8){
            hist[lane*428 + 255] = PL[lane*257 + 255];       // w[255] = P[255]
            oL[lane*257 + 255] = 0.f;                        // beta[255] = 0
        }
        float Aown = Akc[3*n], Aoth = Akc[n+1];
        float EAo = __expf(Aown);
        float EAx = __expf(Aoth);
        float Ewp, pre[4];
        for (int t0 = TT_-32; t0 >= 0; t0 -= 32){
            asm volatile("" ::: "memory");
            // Phase A: window [t0+32, t0+191], mw (+seed scale), E table, ct
            float v[20];
            #pragma unroll
            for (int i = 0; i < 20; ++i) v[i] = hist[g*428 + t0 + 32 + q + 8*i];
            float z[10];
            #pragma unroll
            for (int i = 0; i < 10; ++i) z[i] = fmaxf(v[2*i], v[2*i+1]);
            #pragma unroll
            for (int i = 0; i < 5; ++i) z[i] = fmaxf(z[2*i], z[2*i+1]);
            float mw = fmaxf(fmaxf(fmaxf(z[0],z[1]), fmaxf(z[2],z[3])), z[4]);
            mw = dpp_max8(mw);
            mw = fmaxf(mw, PL[g*257 + 255]);   // covers seed scale (first tile)
            #pragma unroll
            for (int i = 0; i < 20; ++i) EL[g*204 + 32 + q + 8*i] = __expf(v[i] - mw);
            float mwo = dppf<0xB1>(mw);
            #pragma unroll
            for (int j = 0; j < 4; ++j){
                int tt = q + 8*j; int t = t0 + tt;
                float dP = PL[g*257 + t] - PL[go*257 + t];   // +P_n - P_o
                ctL[g*36 + tt] = fminf(EAx * __expf(dP + mwo - mw), 1e15f);
            }
            if (t0 == TT_-32 && r < 2)
                EL[g*204 + 31] = __expf(hist[g*428 + 255] - mw);   // seed at idx 31
            asm volatile("" ::: "memory");
            // Phase B: far convolution (j >= 32)
            for (int tt = 0; tt < 32; ++tt){
                float a0 = 0.f, a1 = 0.f;
                #pragma unroll
                for (int i = 0; i < 16; i += 2){
                    a0 = fmaf(EL[g*204 + tt + 33 + q + 8*i],     Epdf[i],   a0);
                    a1 = fmaf(EL[g*204 + tt + 33 + q + 8*(i+1)], Epdf[i+1], a1);
                }
                float a = dpp_sum8(a0 + a1);
                if (r < 2) fsL[g*36 + tt] = a;
            }
            asm volatile("" ::: "memory");
            // Phase C: serial descending, pure linear
            int tts = (t0 == TT_-32) ? 30 : 31;
            Ewp = EL[g*204 + tts + 1];
            #pragma unroll
            for (int i = 0; i < 4; ++i) pre[i] = EL[g*204 + tts + 1 + q + 8*i];
            for (int tt = tts; tt >= 0; --tt){
                int t = t0 + tt;
                float x0 = ((q == 0) ? Ewp : pre[0]) * Epdn[0];
                float ac = fmaf(pre[1], Epdn[1], x0);
                ac = fmaf(pre[2], Epdn[2], ac);
                ac = fmaf(pre[3], Epdn[3], ac);
                #pragma unroll
                for (int i = 0; i < 4; ++i) pre[i] = EL[g*204 + tt + q + 8*i];
                float W = dpp_sum8(ac) + fsL[g*36 + tt];
                W = fminf(fmaxf(W, 1e-30f), 1e15f);
                float Wo = dppf<0xB1>(W);
                float Ewt = fminf(fmaf(Wo, ctL[g*36 + tt], W*EAo), 1e30f);
                float lE = __logf(Ewt);                  // off critical path
                if (r < 2){
                    EL[g*204 + tt] = Ewt;
                    float wt = lE + mw;
                    hist[g*428 + t] = wt;
                    oL[g*257 + t] = wt - PL[g*257 + t];
                }
                Ewp = Ewt;
            }
        }
        asm volatile("" ::: "memory");
        for (int idx = lane; idx < 4*512; idx += 64){
            int c2 = idx >> 9, j = idx & 511;
            beta[(size_t)(gid0+c2)*512 + j] = oL[(c2*2 + (j>>8))*257 + (j&255)];
        }
    }
}

// ---------- 10. logp_event: recompute alpha on the fly, lse over k (r15 version) ----------
__global__ void k_logpevent(const float* __restrict__ P, const float* __restrict__ s_hist,
                            const float* __restrict__ beta, const float* __restrict__ logp_d,
                            const float* __restrict__ log_lo, const float* __restrict__ log_A,
                            const float* __restrict__ log_pi, const float* __restrict__ Zv,
                            float* __restrict__ out){
    int bid = blockIdx.x;                  // ((b*C+c)*2+n)*156 + d
    int d = bid % DD_; int rem = bid / DD_;
    int n = rem & 1; int cc = (rem >> 1) % CC_; int b = rem / (2*CC_);
    int t = threadIdx.x;
    float m = -1e30f, s = 0.f;
    for (int k = 0; k < KK_; ++k){
        const float* Pn  = P + (((b*KK_+k)*CC_+cc)*2 + n)*TT_;
        const float* pdn = logp_d + ((k*CC_+cc)*2 + n)*DD_;
        float alpha;
        if (d > t){
            alpha = NEGC;
        } else if (d == t){
            alpha = log_lo[(k*CC_+cc)*2 + n] + pdn[t] + Pn[t];
        } else {
            const float* sh = s_hist + (((b*KK_+k)*CC_+cc)*2)*TT_;
            float u0 = sh[t-1-d]       + log_A[(k*CC_+cc)*4 + n];
            float u1 = sh[TT_ + t-1-d] + log_A[(k*CC_+cc)*4 + 2 + n];
            float tr = lse2_fast(u0, u1);
            alpha = tr + pdn[d] + (Pn[t] - Pn[t-1-d]);
        }
        float term = log_pi[b*KK_ + k] + alpha
                   + beta[(((b*KK_+k)*CC_+cc)*2 + n)*TT_ + t]
                   - Zv[(b*KK_+k)*CC_ + cc];
        lse_acc_fast(m, s, term);
    }
    out[(size_t)bid*TT_ + t] = m + __logf(s);
}

// ---------- 11. lj partials: one block per (bcn, chunk of 39 rows), linear sums ----------
__global__ __launch_bounds__(256) void k_lj(const float* __restrict__ lp_all,
                                            float* __restrict__ ljpart){
    int blk = blockIdx.x;
    int bcn = blk >> 2; int chunk = blk & 3;
    int d0 = chunk * 39;
    const float* lp = lp_all + (size_t)bcn*DD_*TT_;
    int tid = threadIdx.x;
    int wv = tid >> 6; int ln = tid & 63;
    __shared__ float Rp[39][TT_+1];
    for (int rr = wv; rr < 39; rr += 4){
        const float* row = lp + (d0 + rr)*TT_;
        float carry = 0.f;
        if (ln == 0) Rp[rr][0] = 0.f;
        #pragma unroll
        for (int seg = 0; seg < 4; ++seg){
            float v = __expf(fminf(row[seg*64 + ln], 60.f));
            #pragma unroll
            for (int off = 1; off < 64; off <<= 1){
                float u = __shfl_up(v, off);
                if (ln >= off) v += u;
            }
            v += carry;
            Rp[rr][1 + seg*64 + ln] = v;
            carry = __shfl(v, 63);
        }
    }
    __syncthreads();
    float acc = 0.f;
    int t = tid;
    #pragma unroll 4
    for (int rr = 0; rr < 39; ++rr){
        int d = d0 + rr;
        int lo = max(t, d);
        int hi = min(t + d, TT_-1);
        acc += Rp[rr][hi+1] - Rp[rr][lo];
    }
    ljpart[(bcn*4 + chunk)*TT_ + t] = acc;   // linear space
}

// ---------- 12. p_frame from linear partials ----------
__global__ void k_pframe(const float* __restrict__ ljpart, float* __restrict__ out2){
    int idx = blockIdx.x*256 + threadIdx.x;   // (b*C+c)*T + t
    int t = idx & 255; int bc = idx >> 8;
    const float* p0 = ljpart + (size_t)(bc*2 + 0)*4*TT_;
    const float* p1 = ljpart + (size_t)(bc*2 + 1)*4*TT_;
    float s0 = (p0[t] + p0[TT_+t]) + (p0[2*TT_+t] + p0[3*TT_+t]);
    float s1 = (p1[t] + p1[TT_+t]) + (p1[2*TT_+t] + p1[3*TT_+t]);
    float l0 = __logf(fmaxf(s0, 1e-38f));
    float l1 = __logf(fmaxf(s1, 1e-38f));
    float mm = fmaxf(l0, l1);
    float e0 = __expf(l0 - mm), e1 = __expf(l1 - mm);
    out2[idx] = e1 / (e0 + e1);
}

// ---------- launch ----------
extern "C" void kernel_launch(void* const* d_in, const int* in_sizes, int n_in,
                              void* d_out, int out_size, void* d_ws, size_t ws_size,
                              hipStream_t stream){
    const float* h         = (const float*)d_in[0];
    const float* logit_lo1 = (const float*)d_in[1];
    const float* log_A     = (const float*)d_in[2];
    const float* dur_conc  = (const float*)d_in[3];
    const float* dur_rate  = (const float*)d_in[4];
    // d_in[5] dur_mix unused (L=1 -> log_softmax == 0)
    const float* w_mix     = (const float*)d_in[6];
    const float* b_mix     = (const float*)d_in[7];
    const float* q_attn    = (const float*)d_in[8];
    const float* w_attn    = (const float*)d_in[9];
    const float* b_attn    = (const float*)d_in[10];
    const float* w_k       = (const float*)d_in[11];
    const float* b_k       = (const float*)d_in[12];
    const float* bn_gamma  = (const float*)d_in[13];
    const float* bn_beta   = (const float*)d_in[14];
    const float* w_em      = (const float*)d_in[15];
    const float* b_em      = (const float*)d_in[16];

    float* out  = (float*)d_out;                        // logp_event (B,C,N,D,T)
    float* out2 = out + (size_t)BB_*CC_*2*DD_*TT_;      // p_frame (B,C,T)

    // workspace carve (floats) — identical to round 15
    float* ws = (float*)d_ws;
    float* Pbuf   = ws;                 ws += BB_*OO_*TT_;
    float* s_hist = ws;                 ws += BB_*OO_*TT_;
    float* beta   = ws;                 ws += BB_*OO_*TT_;
    float* xbn    = ws;                 ws += BB_*FF_*TT_;
    float* xm     = ws;                 ws += BB_*FF_*TT_;
    float* xmT    = ws;                 ws += BB_*FF_*TT_;
    float* logp_d = ws;                 ws += KK_*CC_*2*DD_;
    float* log_lo = ws;                 ws += KK_*CC_*2;
    float* log_pi = ws;                 ws += BB_*KK_;
    float* Zv     = ws;                 ws += BB_*KK_*CC_;
    float* meanv  = ws;                 ws += FF_;
    float* rstdv  = ws;                 ws += FF_;
    float* ljpart = ws;                 ws += BB_*CC_*2*4*TT_;

    hipLaunchKernelGGL(k_bnstats_logpd, dim3(FF_ + KK_*CC_*2), dim3(256), 0, stream,
                       h, meanv, rstdv, dur_conc, dur_rate, logit_lo1, logp_d, log_lo);
    hipLaunchKernelGGL(k_bnapply,  dim3(BB_*FF_),       dim3(256), 0, stream, h, meanv, rstdv, bn_gamma, bn_beta, xbn);
    hipLaunchKernelGGL(k_gemm_em,  dim3(BB_*OO_),       dim3(256), 0, stream, xbn, w_em, b_em, Pbuf);
    hipLaunchKernelGGL(k_scan_mix, dim3(2*BB_*KK_*CC_/4 + BB_*FF_), dim3(256), 0, stream,
                       Pbuf, logp_d, log_lo, log_A, s_hist, Zv, beta,
                       h, w_mix, b_mix, xm, xmT);
    hipLaunchKernelGGL(k_attnpool, dim3(BB_),           dim3(256), 0, stream, xm, xmT, q_attn, w_attn, b_attn, w_k, b_k, log_pi);
    hipLaunchKernelGGL(k_logpevent,dim3(BB_*CC_*2*DD_), dim3(256), 0, stream, Pbuf, s_hist, beta, logp_d, log_lo, log_A, log_pi, Zv, out);
    hipLaunchKernelGGL(k_lj,       dim3(BB_*CC_*2*4),   dim3(256), 0, stream, out, ljpart);
    hipLaunchKernelGGL(k_pframe,   dim3(BB_*CC_),       dim3(256), 0, stream, ljpart, out2);
}

// Round 19
// 236.135 us; speedup vs baseline: 1.2886x; 1.0486x over previous
//
#include <hip/hip_runtime.h>
#include <math.h>

// Problem constants
#define BB_ 4
#define FF_ 256
#define TT_ 256
#define KK_ 8
#define CC_ 10
#define DD_ 156
#define OO_ 160   // K*C*N
#define NEGC (-1e9f)

// ---------- helpers ----------
__device__ __forceinline__ float softplusf(float x){
    return fmaxf(x, 0.f) + log1pf(expf(-fabsf(x)));
}
__device__ __forceinline__ float lse2f(float a, float b){
    float m = fmaxf(a, b);
    return m + logf(expf(a-m) + expf(b-m));
}
__device__ __forceinline__ float lse2_fast(float a, float b){
    float m = fmaxf(a, b);
    return m + __logf(__expf(a-m) + __expf(b-m));
}
__device__ __forceinline__ void lse_acc(float &m, float &s, float x){
    if (x > m){ s = s*expf(m-x) + 1.f; m = x; }
    else        s += expf(x-m);
}
__device__ __forceinline__ void lse_acc_fast(float &m, float &s, float x){
    if (x > m){ s = s*__expf(m-x) + 1.f; m = x; }
    else        s += __expf(x-m);
}
__device__ __forceinline__ void wave_lse_reduce(float &m, float &s){
    for (int off = 32; off; off >>= 1){
        float m2 = __shfl_xor(m, off);
        float s2 = __shfl_xor(s, off);
        float M  = fmaxf(m, m2);
        s = s*expf(m-M) + s2*expf(m2-M);
        m = M;
    }
}
// DPP move (compile-time ctrl). row_ror:N = 0x120+N; quad_perm[1,0,3,2] = 0xB1.
template<int CTRL>
__device__ __forceinline__ float dppf(float v){
    return __int_as_float(__builtin_amdgcn_update_dpp(
        0, __float_as_int(v), CTRL, 0xF, 0xF, false));
}
__device__ __forceinline__ float dpp_sum8(float a){
    a = a + dppf<0x122>(a);
    a = a + dppf<0x124>(a);
    a = a + dppf<0x128>(a);
    return a;
}
__device__ __forceinline__ float dpp_max8(float a){
    a = fmaxf(a, dppf<0x122>(a));
    a = fmaxf(a, dppf<0x124>(a));
    a = fmaxf(a, dppf<0x128>(a));
    return a;
}

// ---------- 1. bnstats (blocks [0,256)) ∥ logpd (blocks [256,416)) ----------
__global__ void k_bnstats_logpd(const float* __restrict__ h, float* __restrict__ meanv,
                                float* __restrict__ rstdv,
                                const float* __restrict__ conc, const float* __restrict__ rate,
                                const float* __restrict__ logit_lo1, float* __restrict__ logp_d,
                                float* __restrict__ log_lo){
    if (blockIdx.x >= FF_){
        // ---- logpd part (one wave per (k,c,n)) ----
        if (threadIdx.x >= 64) return;
        int kcn = blockIdx.x - FF_;   // (k*C+c)*2+n
        int lane = threadIdx.x;
        float a  = softplusf(conc[kcn]) + 1e-4f;
        float bb = softplusf(rate[kcn]) + 1e-4f;
        float base = a*logf(bb) - lgammaf(a);
        float vals[3]; int ds[3]; int cnt = 0;
        float m = -1e30f, s = 0.f;
        for (int i = 0; i < 3; ++i){
            int d = lane + i*64;
            if (d < DD_){
                float dv = (float)(d+1);
                float x = base + (a - 1.f)*logf(dv) - bb*dv;
                vals[cnt] = x; ds[cnt] = d; ++cnt;
                lse_acc(m, s, x);
            }
        }
        wave_lse_reduce(m, s);
        float total = m + logf(s);
        for (int i = 0; i < cnt; ++i) logp_d[kcn*DD_ + ds[i]] = vals[i] - total;
        if (lane == 0){
            float x = logit_lo1[kcn >> 1];
            float xx = (kcn & 1) ? -x : x;
            log_lo[kcn] = -softplusf(-xx);   // log_sigmoid
        }
        return;
    }
    // ---- bnstats part ----
    int f = blockIdx.x; int tid = threadIdx.x;
    float s = 0.f, s2 = 0.f;
    for (int b = 0; b < BB_; ++b){
        float v = h[(b*FF_ + f)*TT_ + tid];
        s += v; s2 += v*v;
    }
    __shared__ float rs[4], rs2[4];
    for (int off = 32; off; off >>= 1){ s += __shfl_xor(s, off); s2 += __shfl_xor(s2, off); }
    if ((tid & 63) == 0){ rs[tid>>6] = s; rs2[tid>>6] = s2; }
    __syncthreads();
    if (tid == 0){
        float S = rs[0]+rs[1]+rs[2]+rs[3];
        float S2 = rs2[0]+rs2[1]+rs2[2]+rs2[3];
        float mean = S / 1024.f;
        float var = S2 / 1024.f - mean*mean;
        meanv[f] = mean;
        rstdv[f] = rsqrtf(var + 1e-5f);
    }
}

// ---------- 3. emission GEMM with inline BN+relu + fused prefix over t -> P ----------
// xbn never materialized: x = relu(h*a_f + b_f), a=rstd*gamma, b=beta-mean*a (LDS).
__global__ void k_gemm_em(const float* __restrict__ h, const float* __restrict__ meanv,
                          const float* __restrict__ rstdv, const float* __restrict__ gamma,
                          const float* __restrict__ betav, const float* __restrict__ w_em,
                          const float* __restrict__ b_em, float* __restrict__ Pout){
    int bid = blockIdx.x;                 // b*160 + o
    int b = bid / OO_, o = bid % OO_;
    int t = threadIdx.x;
    __shared__ float af[256], bf[256], buf[256];
    {
        float sc = rstdv[t] * gamma[t];
        af[t] = sc;
        bf[t] = betav[t] - meanv[t]*sc;
    }
    __syncthreads();
    const float* hb = h + b*FF_*TT_ + t;
    const float* wr = w_em + o*FF_;
    float acc = b_em[o];
    #pragma unroll 8
    for (int f = 0; f < FF_; ++f){
        float xv = fmaxf(fmaf(hb[f*TT_], af[f], bf[f]), 0.f);
        acc = fmaf(wr[f], xv, acc);
    }
    buf[t] = acc; __syncthreads();
    for (int off = 1; off < 256; off <<= 1){
        float x = (t >= off) ? buf[t-off] : 0.f;
        __syncthreads();
        buf[t] += x;
        __syncthreads();
    }
    Pout[bid*TT_ + t] = buf[t];
}

// ---------- 5. attention pool -> log_pi (one block per b) ----------
__global__ void k_attnpool(const float* __restrict__ xm, const float* __restrict__ xmT,
                           const float* __restrict__ q,
                           const float* __restrict__ w_attn, const float* __restrict__ b_attn,
                           const float* __restrict__ w_k, const float* __restrict__ b_k,
                           float* __restrict__ log_pi){
    int b = blockIdx.x; int tid = threadIdx.x;
    __shared__ float sc[256], pooled[256], zs[256], red[8];
    const float* xb = xm + b*FF_*TT_;
    float acc = 0.f;
    for (int f = 0; f < FF_; ++f) acc += q[f] * xb[f*TT_ + tid];
    sc[tid] = acc; __syncthreads();
    float v = sc[tid];
    float m = v;
    for (int off = 32; off; off >>= 1) m = fmaxf(m, __shfl_xor(m, off));
    if ((tid & 63) == 0) red[tid>>6] = m;
    __syncthreads();
    m = fmaxf(fmaxf(red[0], red[1]), fmaxf(red[2], red[3]));
    float e = expf(v - m);
    float ssum = e;
    for (int off = 32; off; off >>= 1) ssum += __shfl_xor(ssum, off);
    if ((tid & 63) == 0) red[4 + (tid>>6)] = ssum;
    __syncthreads();
    ssum = red[4]+red[5]+red[6]+red[7];
    __syncthreads();
    sc[tid] = e / ssum; __syncthreads();
    const float* xT = xmT + b*TT_*FF_;
    float pacc = 0.f;
    for (int t2 = 0; t2 < TT_; ++t2) pacc += xT[t2*FF_ + tid] * sc[t2];
    pooled[tid] = pacc; __syncthreads();
    int wv = tid >> 6; int ln = tid & 63;
    for (int ii = 0; ii < 64; ++ii){
        int i = wv*64 + ii;
        float za = 0.f;
        #pragma unroll
        for (int ff = 0; ff < 4; ++ff) za += pooled[ln + 64*ff] * w_attn[i*FF_ + ln + 64*ff];
        for (int off = 32; off; off >>= 1) za += __shfl_xor(za, off);
        if (ln == 0) zs[i] = za + b_attn[i];
    }
    __syncthreads();
    if (wv == 0){
        for (int kk2 = 0; kk2 < KK_; ++kk2){
            float za = 0.f;
            #pragma unroll
            for (int ff = 0; ff < 4; ++ff) za += zs[ln + 64*ff] * w_k[kk2*FF_ + ln + 64*ff];
            for (int off = 32; off; off >>= 1) za += __shfl_xor(za, off);
            if (ln == 0) red[kk2] = za + b_k[kk2];
        }
    }
    __syncthreads();
    if (tid == 0){
        float mm = -1e30f;
        for (int i = 0; i < KK_; ++i) mm = fmaxf(mm, red[i]);
        float su = 0.f;
        for (int i = 0; i < KK_; ++i) su += expf(red[i] - mm);
        sc[0] = mm + logf(su);
    }
    __syncthreads();
    if (tid < KK_) log_pi[b*KK_ + tid] = red[tid] - sc[0];
}

// ---------- 8. MEGA kernel: HSMM scan (blocks [0,160), wave 0 only)
// ∥ mixture GEMM (blocks [160,1184)) — byte-identical to round 15 ----------
__global__ __launch_bounds__(256) void k_scan_mix(const float* __restrict__ P,
                          const float* __restrict__ logp_d,
                          const float* __restrict__ log_lo, const float* __restrict__ log_A,
                          float* __restrict__ s_hist, float* __restrict__ Zout,
                          float* __restrict__ beta,
                          const float* __restrict__ h, const float* __restrict__ w_mix,
                          const float* __restrict__ b_mix, float* __restrict__ xm,
                          float* __restrict__ xmT){
    __shared__ float L[11056];
    if (blockIdx.x >= 2*BB_*KK_*CC_/4){
        // ---------------- gemm_mix part ----------------
        int bid = blockIdx.x - 2*BB_*KK_*CC_/4;   // b*256 + o
        int b = bid >> 8, o = bid & 255;
        int t = threadIdx.x;
        const float* hb = h + b*FF_*TT_ + t;
        const float* wr = w_mix + o*FF_;
        float acc = b_mix[o];
        #pragma unroll 8
        for (int f = 0; f < FF_; ++f) acc += wr[f] * hb[f*TT_];
        float v = fmaxf(acc, 0.f);
        xm[bid*TT_ + t] = v;
        xmT[(b*TT_ + t)*FF_ + o] = v;
        return;
    }
    if (threadIdx.x >= 64) return;        // scan uses a single wave; no barriers below
    int sbid = blockIdx.x;
    float* hist = L;              // [8][424] fwd: log trm, idx=160+tau (guard [0,160)); bwd: log w, idx=tau (guard [256,424))
    float* pdL  = L + 8*424;      // [8][168]
    float* EL   = pdL + 8*168;    // [8][204] scaled-linear table (192 used)
    float* PL   = EL + 8*204;     // [8][257]
    float* oL   = PL + 8*257;     // [8][257] fwd: s log staging; bwd: bl staging
    float* fsL  = oL + 8*257;     // [8][36]  init+far sums (linear)
    float* ctL  = fsL + 8*36;     // [8][36]  cross-state factors (linear)
    int lane = threadIdx.x;
    int ch = lane >> 4, r = lane & 15, n = r & 1, q = r >> 1;
    int g = ch*2 + n, go = g ^ 1;
    bool fwd = sbid < (BB_*KK_*CC_/4);
    int gid0 = (fwd ? sbid : sbid - BB_*KK_*CC_/4) * 4;
    int dlim = fwd ? DD_ : (DD_-1);
    for (int idx = lane; idx < 8*168; idx += 64){
        int g2 = idx/168, d2 = idx%168;
        int gg = gid0 + (g2>>1); int c3 = gg % CC_, k3 = (gg/CC_) % KK_;
        pdL[g2*168 + d2] = (d2 < dlim) ? logp_d[((k3*CC_+c3)*2+(g2&1))*DD_ + d2] : -1e30f;
    }
    for (int idx = lane; idx < 4*512; idx += 64){
        int c2 = idx >> 9, j = idx & 511;
        PL[(c2*2 + (j>>8))*257 + (j&255)] = P[(size_t)(gid0+c2)*512 + j];
    }
    int gidc = gid0 + ch; int c = gidc % CC_, k = (gidc/CC_) % KK_;
    const float* Akc = log_A + (k*CC_+c)*4;
    float Epdn[4], Epdf[16];
    #pragma unroll
    for (int i = 0; i < 4; ++i)  Epdn[i] = __expf(pdL[g*168 + q + 8*i]);
    #pragma unroll
    for (int i = 0; i < 16; ++i) Epdf[i] = __expf(pdL[g*168 + 32 + q + 8*i]);

    if (fwd){
        for (int idx = lane; idx < 8*160; idx += 64)
            hist[(idx/160)*424 + (idx%160)] = -1e30f;     // guard below tau=0
        float Aself = Akc[3*n], Across = Akc[2-n];
        float EAs = __expf(Aself);
        float EAc = __expf(Across);
        float llo = log_lo[(k*CC_+c)*2 + n];
        float Etp, pre[4];
        for (int t0 = 0; t0 < TT_; t0 += 32){
            asm volatile("" ::: "memory");
            // Phase A: window max (+init scale), E table, ct factors
            float v[20];
            #pragma unroll
            for (int i = 0; i < 20; ++i) v[i] = hist[g*424 + t0 + q + 8*i];
            float z[10];
            #pragma unroll
            for (int i = 0; i < 10; ++i) z[i] = fmaxf(v[2*i], v[2*i+1]);
            #pragma unroll
            for (int i = 0; i < 5; ++i) z[i] = fmaxf(z[2*i], z[2*i+1]);
            float mt = fmaxf(fmaxf(fmaxf(z[0],z[1]), fmaxf(z[2],z[3])), z[4]);
            mt = dpp_max8(mt);
            float pm = -1e30f;
            #pragma unroll
            for (int j = 0; j < 4; ++j){
                int t = t0 + q + 8*j;
                pm = fmaxf(pm, (t < 168) ? pdL[g*168 + t] : -1e30f);
            }
            pm = dpp_max8(pm);
            mt = fmaxf(mt, llo + pm);          // finite always; scales init <= 1
            #pragma unroll
            for (int i = 0; i < 20; ++i) EL[g*204 + q + 8*i] = __expf(v[i] - mt);
            float mto = dppf<0xB1>(mt);
            #pragma unroll
            for (int j = 0; j < 4; ++j){
                int tt = q + 8*j; int t = t0 + tt;
                float dP = PL[go*257 + t] - PL[g*257 + t];
                ctL[g*36 + tt] = fminf(EAc * __expf(dP + mto - mt), 1e15f);
            }
            asm volatile("" ::: "memory");
            // Phase B: far convolution + init fold
            for (int tt = 0; tt < 32; ++tt){
                float a0 = 0.f, a1 = 0.f;
                #pragma unroll
                for (int i = 0; i < 16; i += 2){
                    a0 = fmaf(EL[g*204 + 127 + tt - q - 8*i],     Epdf[i],   a0);
                    a1 = fmaf(EL[g*204 + 127 + tt - q - 8*(i+1)], Epdf[i+1], a1);
                }
                float a = dpp_sum8(a0 + a1);
                int t = t0 + tt;
                float pdt = (t < 168) ? pdL[g*168 + t] : -1e30f;
                if (r < 2) fsL[g*36 + tt] = a + __expf(llo + pdt - mt);
            }
            asm volatile("" ::: "memory");
            // Phase C: serial, pure linear
            Etp = EL[g*204 + 159];
            #pragma unroll
            for (int i = 0; i < 4; ++i) pre[i] = EL[g*204 + 159 - q - 8*i];
            for (int tt = 0; tt < 32; ++tt){
                int t = t0 + tt;
                float x0 = ((q == 0) ? Etp : pre[0]) * Epdn[0];
                float ac = fmaf(pre[1], Epdn[1], x0);
                ac = fmaf(pre[2], Epdn[2], ac);
                ac = fmaf(pre[3], Epdn[3], ac);
                #pragma unroll
                for (int i = 0; i < 4; ++i) pre[i] = EL[g*204 + 160 + tt - q - 8*i];
                float S = dpp_sum8(ac) + fsL[g*36 + tt];
                S = fminf(fmaxf(S, 1e-30f), 1e15f);
                float So = dppf<0xB1>(S);
                float Et = fminf(fmaf(So, ctL[g*36 + tt], S*EAs), 1e30f);
                float lS = __logf(S), lE = __logf(Et);   // off critical path
                if (r < 2){
                    EL[g*204 + 160 + tt] = Et;
                    hist[g*424 + 160 + t] = lE + mt;
                    oL[g*257 + t] = lS + mt + PL[g*257 + t];
                }
                Etp = Et;
            }
        }
        asm volatile("" ::: "memory");
        for (int idx = lane; idx < 4*512; idx += 64){
            int c2 = idx >> 9, j = idx & 511;
            s_hist[(size_t)(gid0+c2)*512 + j] = oL[(c2*2 + (j>>8))*257 + (j&255)];
        }
        if (r == 0) Zout[gidc] = lse2f(oL[(ch*2)*257 + 255], oL[(ch*2+1)*257 + 255]);
    } else {
        for (int idx = lane; idx < 8*168; idx += 64)
            hist[(idx/168)*424 + 256 + (idx%168)] = -1e30f;  // guard above tau=255
        if (lane < 8){
            hist[lane*424 + 255] = PL[lane*257 + 255];       // w[255] = P[255]
            oL[lane*257 + 255] = 0.f;                        // beta[255] = 0
        }
        float Aown = Akc[3*n], Aoth = Akc[n+1];
        float EAo = __expf(Aown);
        float EAx = __expf(Aoth);
        float Ewp, pre[4];
        for (int t0 = TT_-32; t0 >= 0; t0 -= 32){
            asm volatile("" ::: "memory");
            // Phase A: window [t0+32, t0+191], mw (+seed scale), E table, ct
            float v[20];
            #pragma unroll
            for (int i = 0; i < 20; ++i) v[i] = hist[g*424 + t0 + 32 + q + 8*i];
            float z[10];
            #pragma unroll
            for (int i = 0; i < 10; ++i) z[i] = fmaxf(v[2*i], v[2*i+1]);
            #pragma unroll
            for (int i = 0; i < 5; ++i) z[i] = fmaxf(z[2*i], z[2*i+1]);
            float mw = fmaxf(fmaxf(fmaxf(z[0],z[1]), fmaxf(z[2],z[3])), z[4]);
            mw = dpp_max8(mw);
            mw = fmaxf(mw, PL[g*257 + 255]);   // covers seed scale (first tile)
            #pragma unroll
            for (int i = 0; i < 20; ++i) EL[g*204 + 32 + q + 8*i] = __expf(v[i] - mw);
            float mwo = dppf<0xB1>(mw);
            #pragma unroll
            for (int j = 0; j < 4; ++j){
                int tt = q + 8*j; int t = t0 + tt;
                float dP = PL[g*257 + t] - PL[go*257 + t];   // +P_n - P_o
                ctL[g*36 + tt] = fminf(EAx * __expf(dP + mwo - mw), 1e15f);
            }
            if (t0 == TT_-32 && r < 2)
                EL[g*204 + 31] = __expf(hist[g*424 + 255] - mw);   // seed at idx 31
            asm volatile("" ::: "memory");
            // Phase B: far convolution (j >= 32)
            for (int tt = 0; tt < 32; ++tt){
                float a0 = 0.f, a1 = 0.f;
                #pragma unroll
                for (int i = 0; i < 16; i += 2){
                    a0 = fmaf(EL[g*204 + tt + 33 + q + 8*i],     Epdf[i],   a0);
                    a1 = fmaf(EL[g*204 + tt + 33 + q + 8*(i+1)], Epdf[i+1], a1);
                }
                float a = dpp_sum8(a0 + a1);
                if (r < 2) fsL[g*36 + tt] = a;
            }
            asm volatile("" ::: "memory");
            // Phase C: serial descending, pure linear
            int tts = (t0 == TT_-32) ? 30 : 31;
            Ewp = EL[g*204 + tts + 1];
            #pragma unroll
            for (int i = 0; i < 4; ++i) pre[i] = EL[g*204 + tts + 1 + q + 8*i];
            for (int tt = tts; tt >= 0; --tt){
                int t = t0 + tt;
                float x0 = ((q == 0) ? Ewp : pre[0]) * Epdn[0];
                float ac = fmaf(pre[1], Epdn[1], x0);
                ac = fmaf(pre[2], Epdn[2], ac);
                ac = fmaf(pre[3], Epdn[3], ac);
                #pragma unroll
                for (int i = 0; i < 4; ++i) pre[i] = EL[g*204 + tt + q + 8*i];
                float W = dpp_sum8(ac) + fsL[g*36 + tt];
                W = fminf(fmaxf(W, 1e-30f), 1e15f);
                float Wo = dppf<0xB1>(W);
                float Ewt = fminf(fmaf(Wo, ctL[g*36 + tt], W*EAo), 1e30f);
                float lE = __logf(Ewt);                  // off critical path
                if (r < 2){
                    EL[g*204 + tt] = Ewt;
                    float wt = lE + mw;
                    hist[g*424 + t] = wt;
                    oL[g*257 + t] = wt - PL[g*257 + t];
                }
                Ewp = Ewt;
            }
        }
        asm volatile("" ::: "memory");
        for (int idx = lane; idx < 4*512; idx += 64){
            int c2 = idx >> 9, j = idx & 511;
            beta[(size_t)(gid0+c2)*512 + j] = oL[(c2*2 + (j>>8))*257 + (j&255)];
        }
    }
}

// ---------- 9. trm precompute (in-place on s_hist; thread-local read-then-write) ----------
// trm[n][tau] = lse2(s0[tau]+A[0][n], s1[tau]+A[1][n]) - P_n[tau]
__global__ void k_trm(float* __restrict__ s_hist, const float* __restrict__ P,
                      const float* __restrict__ log_A){
    int chain = blockIdx.x;            // (b*K+k)*C+c
    int t = threadIdx.x;
    int c = chain % CC_, k = (chain/CC_) % KK_;
    const float* Akc = log_A + (k*CC_+c)*4;
    size_t base = (size_t)chain*512;
    float s0 = s_hist[base + t];
    float s1 = s_hist[base + 256 + t];
    float P0 = P[base + t];
    float P1 = P[base + 256 + t];
    float trm0 = lse2_fast(s0 + Akc[0], s1 + Akc[2]) - P0;
    float trm1 = lse2_fast(s0 + Akc[1], s1 + Akc[3]) - P1;
    s_hist[base + t]       = trm0;
    s_hist[base + 256 + t] = trm1;
}

// ---------- 10. logp_event via trm identity: alpha = trm[tau] + pd[d] + P[t] ----------
__global__ void k_logpevent(const float* __restrict__ P, const float* __restrict__ trm,
                            const float* __restrict__ beta, const float* __restrict__ logp_d,
                            const float* __restrict__ log_lo, const float* __restrict__ log_pi,
                            const float* __restrict__ Zv, float* __restrict__ out){
    int bid = blockIdx.x;                  // ((b*C+c)*2+n)*156 + d
    int d = bid % DD_; int rem = bid / DD_;
    int n = rem & 1; int cc = (rem >> 1) % CC_; int b = rem / (2*CC_);
    int t = threadIdx.x;
    int tau = t - 1 - d; int tauc = tau < 0 ? 0 : tau;
    float m = -1e30f, s = 0.f;
    for (int k = 0; k < KK_; ++k){
        int gk = ((b*KK_+k)*CC_+cc)*2 + n;
        int kc = (k*CC_+cc)*2 + n;
        float lpz = log_pi[b*KK_ + k] - Zv[(b*KK_+k)*CC_ + cc];
        const float* Pn = P + (size_t)gk*TT_;
        float alpha;
        if (d > t){
            alpha = NEGC;
        } else if (d == t){
            alpha = log_lo[kc] + logp_d[kc*DD_ + t] + Pn[t];
        } else {
            alpha = trm[(size_t)gk*TT_ + tauc] + logp_d[kc*DD_ + d] + Pn[t];
        }
        lse_acc_fast(m, s, lpz + alpha + beta[(size_t)gk*TT_ + t]);
    }
    out[(size_t)bid*TT_ + t] = m + __logf(s);
}

// ---------- 11. lj partials: one block per (bcn, chunk of 39 rows), linear sums ----------
__global__ __launch_bounds__(256) void k_lj(const float* __restrict__ lp_all,
                                            float* __restrict__ ljpart){
    int blk = blockIdx.x;
    int bcn = blk >> 2; int chunk = blk & 3;
    int d0 = chunk * 39;
    const float* lp = lp_all + (size_t)bcn*DD_*TT_;
    int tid = threadIdx.x;
    int wv = tid >> 6; int ln = tid & 63;
    __shared__ float Rp[39][TT_+1];
    for (int rr = wv; rr < 39; rr += 4){
        const float* row = lp + (d0 + rr)*TT_;
        float carry = 0.f;
        if (ln == 0) Rp[rr][0] = 0.f;
        #pragma unroll
        for (int seg = 0; seg < 4; ++seg){
            float v = __expf(fminf(row[seg*64 + ln], 60.f));
            #pragma unroll
            for (int off = 1; off < 64; off <<= 1){
                float u = __shfl_up(v, off);
                if (ln >= off) v += u;
            }
            v += carry;
            Rp[rr][1 + seg*64 + ln] = v;
            carry = __shfl(v, 63);
        }
    }
    __syncthreads();
    float acc = 0.f;
    int t = tid;
    #pragma unroll 4
    for (int rr = 0; rr < 39; ++rr){
        int d = d0 + rr;
        int lo = max(t, d);
        int hi = min(t + d, TT_-1);
        acc += Rp[rr][hi+1] - Rp[rr][lo];
    }
    ljpart[(bcn*4 + chunk)*TT_ + t] = acc;   // linear space
}

// ---------- 12. p_frame from linear partials ----------
__global__ void k_pframe(const float* __restrict__ ljpart, float* __restrict__ out2){
    int idx = blockIdx.x*256 + threadIdx.x;   // (b*C+c)*T + t
    int t = idx & 255; int bc = idx >> 8;
    const float* p0 = ljpart + (size_t)(bc*2 + 0)*4*TT_;
    const float* p1 = ljpart + (size_t)(bc*2 + 1)*4*TT_;
    float s0 = (p0[t] + p0[TT_+t]) + (p0[2*TT_+t] + p0[3*TT_+t]);
    float s1 = (p1[t] + p1[TT_+t]) + (p1[2*TT_+t] + p1[3*TT_+t]);
    float l0 = __logf(fmaxf(s0, 1e-38f));
    float l1 = __logf(fmaxf(s1, 1e-38f));
    float mm = fmaxf(l0, l1);
    float e0 = __expf(l0 - mm), e1 = __expf(l1 - mm);
    out2[idx] = e1 / (e0 + e1);
}

// ---------- launch ----------
extern "C" void kernel_launch(void* const* d_in, const int* in_sizes, int n_in,
                              void* d_out, int out_size, void* d_ws, size_t ws_size,
                              hipStream_t stream){
    const float* h         = (const float*)d_in[0];
    const float* logit_lo1 = (const float*)d_in[1];
    const float* log_A     = (const float*)d_in[2];
    const float* dur_conc  = (const float*)d_in[3];
    const float* dur_rate  = (const float*)d_in[4];
    // d_in[5] dur_mix unused (L=1 -> log_softmax == 0)
    const float* w_mix     = (const float*)d_in[6];
    const float* b_mix     = (const float*)d_in[7];
    const float* q_attn    = (const float*)d_in[8];
    const float* w_attn    = (const float*)d_in[9];
    const float* b_attn    = (const float*)d_in[10];
    const float* w_k       = (const float*)d_in[11];
    const float* b_k       = (const float*)d_in[12];
    const float* bn_gamma  = (const float*)d_in[13];
    const float* bn_beta   = (const float*)d_in[14];
    const float* w_em      = (const float*)d_in[15];
    const float* b_em      = (const float*)d_in[16];

    float* out  = (float*)d_out;                        // logp_event (B,C,N,D,T)
    float* out2 = out + (size_t)BB_*CC_*2*DD_*TT_;      // p_frame (B,C,T)

    // workspace carve (floats) — xbn dropped (BN inlined into gemm_em)
    float* ws = (float*)d_ws;
    float* Pbuf   = ws;                 ws += BB_*OO_*TT_;
    float* s_hist = ws;                 ws += BB_*OO_*TT_;   // becomes trm after k_trm
    float* beta   = ws;                 ws += BB_*OO_*TT_;
    float* xm     = ws;                 ws += BB_*FF_*TT_;
    float* xmT    = ws;                 ws += BB_*FF_*TT_;
    float* logp_d = ws;                 ws += KK_*CC_*2*DD_;
    float* log_lo = ws;                 ws += KK_*CC_*2;
    float* log_pi = ws;                 ws += BB_*KK_;
    float* Zv     = ws;                 ws += BB_*KK_*CC_;
    float* meanv  = ws;                 ws += FF_;
    float* rstdv  = ws;                 ws += FF_;
    float* ljpart = ws;                 ws += BB_*CC_*2*4*TT_;

    hipLaunchKernelGGL(k_bnstats_logpd, dim3(FF_ + KK_*CC_*2), dim3(256), 0, stream,
                       h, meanv, rstdv, dur_conc, dur_rate, logit_lo1, logp_d, log_lo);
    hipLaunchKernelGGL(k_gemm_em,  dim3(BB_*OO_),       dim3(256), 0, stream,
                       h, meanv, rstdv, bn_gamma, bn_beta, w_em, b_em, Pbuf);
    hipLaunchKernelGGL(k_scan_mix, dim3(2*BB_*KK_*CC_/4 + BB_*FF_), dim3(256), 0, stream,
                       Pbuf, logp_d, log_lo, log_A, s_hist, Zv, beta,
                       h, w_mix, b_mix, xm, xmT);
    hipLaunchKernelGGL(k_trm,      dim3(BB_*KK_*CC_),   dim3(256), 0, stream, s_hist, Pbuf, log_A);
    hipLaunchKernelGGL(k_attnpool, dim3(BB_),           dim3(256), 0, stream, xm, xmT, q_attn, w_attn, b_attn, w_k, b_k, log_pi);
    hipLaunchKernelGGL(k_logpevent,dim3(BB_*CC_*2*DD_), dim3(256), 0, stream, Pbuf, s_hist, beta, logp_d, log_lo, log_pi, Zv, out);
    hipLaunchKernelGGL(k_lj,       dim3(BB_*CC_*2*4),   dim3(256), 0, stream, out, ljpart);
    hipLaunchKernelGGL(k_pframe,   dim3(BB_*CC_),       dim3(256), 0, stream, ljpart, out2);
}